// Round 1
// 1703.483 us; speedup vs baseline: 6.7726x; 6.7726x over previous
//
#include <hip/hip_runtime.h>
#include <stdint.h>
#include <stdio.h>

#define ND 100000
#define NG 100000
#define NE 250000
#define NNODE 100000
#define NB 391          // ceil(NNODE/256)
#define OSTRIDE 100016  // ints per etype in the CSR-offsets region (100001 rounded up)

typedef __attribute__((ext_vector_type(8))) short short8;
typedef __attribute__((ext_vector_type(4))) int   int4v;
typedef __attribute__((ext_vector_type(2))) int   int2v;
typedef __attribute__((ext_vector_type(4))) float f32x4;

__device__ __forceinline__ float bf2f(short s) {
  union { unsigned u; float f; } v;
  v.u = ((unsigned)(unsigned short)s) << 16;
  return v.f;
}
__device__ __forceinline__ short f2bf_rne(float f) {
  union { float f; unsigned u; } v;
  v.f = f;
  unsigned u = v.u + 0x7FFFu + ((v.u >> 16) & 1u);
  return (short)(u >> 16);
}

// ---- dtype detection: flags[0]=features are f32, flags[1]=indices are int64 ----
__global__ void detect_kernel(const unsigned short* __restrict__ xs,
                              const int* __restrict__ idx, int* __restrict__ flags) {
  __shared__ int cnt_huge, cnt_oddnz;
  if (threadIdx.x == 0) { cnt_huge = 0; cnt_oddnz = 0; }
  __syncthreads();
  int t = threadIdx.x;
  int h = 0;
#pragma unroll
  for (int i = 0; i < 8; ++i) {
    unsigned e = ((unsigned)xs[t * 8 + i] >> 7) & 0xFFu;
    if (e >= 0xC0u) ++h;  // |v| >= 2^65 or Inf/NaN: impossible for N(0,1) bf16 data
  }
  if (h) atomicAdd(&cnt_huge, h);
  if (t < 128 && idx[2 * t + 1] != 0) atomicAdd(&cnt_oddnz, 1);
  __syncthreads();
  if (t == 0) {
    flags[0] = (cnt_huge > 8) ? 1 : 0;
    flags[1] = (cnt_oddnz == 0) ? 1 : 0;  // int64: odd words all zero (values < 2^31)
  }
}

// ---- degree histogram: deg[idx[e]] += 1 ----
__global__ void hist_kernel(const int* __restrict__ idx, float* __restrict__ deg,
                            const int* __restrict__ flags) {
  int t = blockIdx.x * blockDim.x + threadIdx.x;
  if (t < NE) {
    int v = flags[1] ? idx[2 * (size_t)t] : idx[t];
    atomicAdd(&deg[v], 1.0f);
  }
}

// ---- in-place deg -> rsqrt(max(deg,1)) ----
__global__ void norm_kernel(float* __restrict__ d, int n) {
  int t = blockIdx.x * blockDim.x + threadIdx.x;
  if (t < n) {
    float v = d[t];
    d[t] = rsqrtf(v < 1.0f ? 1.0f : v);
  }
}

// ============ CSR build: 3-kernel exclusive scan over dst degrees + scatter ============
// degbase points at OFF_NRM; dst-degree array for etype et is degbase + (2*et+1)*NNODE.

__global__ void scan_partial(const float* __restrict__ degbase, int* __restrict__ part) {
  int et = blockIdx.y, t = threadIdx.x;
  const float* deg = degbase + (size_t)(2 * et + 1) * NNODE;
  __shared__ int sm[256];
  int i = blockIdx.x * 256 + t;
  int v = (i < NNODE) ? (int)deg[i] : 0;
  sm[t] = v;
  __syncthreads();
  for (int s = 128; s > 0; s >>= 1) {
    if (t < s) sm[t] += sm[t + s];
    __syncthreads();
  }
  if (t == 0) part[et * 512 + blockIdx.x] = sm[0];
}

__global__ void scan_single(int* __restrict__ part) {
  int et = blockIdx.x, t = threadIdx.x;
  __shared__ int sm[512];
  int v = (t < NB) ? part[et * 512 + t] : 0;
  sm[t] = v;
  __syncthreads();
  for (int s = 1; s < 512; s <<= 1) {
    int a = (t >= s) ? sm[t - s] : 0;
    __syncthreads();
    sm[t] += a;
    __syncthreads();
  }
  if (t < NB) part[et * 512 + t] = sm[t] - v;  // exclusive
}

__global__ void scan_final(const float* __restrict__ degbase, const int* __restrict__ part,
                           int* __restrict__ offsbase) {
  int et = blockIdx.y, t = threadIdx.x;
  const float* deg = degbase + (size_t)(2 * et + 1) * NNODE;
  int* offs = offsbase + (size_t)et * OSTRIDE;
  __shared__ int sm[256];
  int i = blockIdx.x * 256 + t;
  int v = (i < NNODE) ? (int)deg[i] : 0;
  sm[t] = v;
  __syncthreads();
  for (int s = 1; s < 256; s <<= 1) {
    int a = (t >= s) ? sm[t - s] : 0;
    __syncthreads();
    sm[t] += a;
    __syncthreads();
  }
  int excl = sm[t] - v;
  int base = part[et * 512 + blockIdx.x];
  if (i < NNODE) offs[i] = base + excl;
  if (i == NNODE - 1) offs[NNODE] = base + excl + v;  // == NE
}

// ---- scatter edges into dst-CSR: srcs[pos]=src, ws[pos]=ns[src] ----
__global__ void csr_scatter(const int* __restrict__ src, const int* __restrict__ dst,
                            const float* __restrict__ ns, const int* __restrict__ offs,
                            int* __restrict__ cur, int* __restrict__ so,
                            float* __restrict__ wo, const int* __restrict__ flags) {
  int t = blockIdx.x * blockDim.x + threadIdx.x;
  if (t >= NE) return;
  int i64 = flags[1];
  int s = i64 ? src[2 * (size_t)t] : src[t];
  int d = i64 ? dst[2 * (size_t)t] : dst[t];
  int pos = offs[d] + atomicAdd(&cur[d], 1);
  so[pos] = s;
  wo[pos] = ns[s];
}

// ---- per-destination gather-aggregate: one wave per dst row, register accumulate,
//      single non-atomic write of y[d] and s[d]. EL = D/64 elements per lane. ----
template <int EL>
__global__ __launch_bounds__(256) void csr_gather(
    const void* __restrict__ x, const int* __restrict__ offs,
    const int* __restrict__ srcs, const float* __restrict__ ws,
    const float* __restrict__ nd, float* __restrict__ y,
    float* __restrict__ sv, const int* __restrict__ flags) {
  constexpr int D = EL * 64;
  int d = blockIdx.x * 4 + (threadIdx.x >> 6);
  if (d >= NNODE) return;
  int lane = threadIdx.x & 63;
  int xf = flags[0];
  int beg = offs[d], end = offs[d + 1];
  float acc[EL];
#pragma unroll
  for (int i = 0; i < EL; ++i) acc[i] = 0.f;
  float sw = 0.f;
  for (int j = beg; j < end; ++j) {
    int s = srcs[j];
    float w = ws[j];
    sw += w;
    if (xf) {
      const float* xp = (const float*)x + (size_t)s * D + lane * EL;
      if constexpr (EL == 8) {
        f32x4 q0 = *(const f32x4*)xp;
        f32x4 q1 = *(const f32x4*)(xp + 4);
#pragma unroll
        for (int i = 0; i < 4; ++i) { acc[i] += w * q0[i]; acc[4 + i] += w * q1[i]; }
      } else {
        f32x4 q0 = *(const f32x4*)xp;
#pragma unroll
        for (int i = 0; i < 4; ++i) acc[i] += w * q0[i];
      }
    } else {
      const short* xp = (const short*)x + (size_t)s * D + lane * EL;
      if constexpr (EL == 8) {
        int4v q = *(const int4v*)xp;
#pragma unroll
        for (int i = 0; i < 4; ++i) {
          unsigned u = (unsigned)q[i];
          union { unsigned u; float f; } lo, hi;
          lo.u = u << 16; hi.u = u & 0xFFFF0000u;
          acc[2 * i] += w * lo.f;
          acc[2 * i + 1] += w * hi.f;
        }
      } else {
        int2v q = *(const int2v*)xp;
#pragma unroll
        for (int i = 0; i < 2; ++i) {
          unsigned u = (unsigned)q[i];
          union { unsigned u; float f; } lo, hi;
          lo.u = u << 16; hi.u = u & 0xFFFF0000u;
          acc[2 * i] += w * lo.f;
          acc[2 * i + 1] += w * hi.f;
        }
      }
    }
  }
  float ndv = nd[d];
#pragma unroll
  for (int i = 0; i < EL; ++i) acc[i] *= ndv;
  float* yp = y + (size_t)d * D + lane * EL;
  f32x4 o0;
#pragma unroll
  for (int i = 0; i < 4; ++i) o0[i] = acc[i];
  *(f32x4*)yp = o0;
  if constexpr (EL == 8) {
    f32x4 o1;
#pragma unroll
    for (int i = 0; i < 4; ++i) o1[i] = acc[4 + i];
    *(f32x4*)(yp + 4) = o1;
  }
  if (lane == 0) sv[d] = ndv * sw;
}

// ---- VT[n,k] = 0.5 * sum_j Ws[k,j] * We[j,n]   (V = Ws@We, stored transposed, bf16)
__global__ void vt_kernel(const void* __restrict__ Ws, const void* __restrict__ We,
                          short* __restrict__ VT, int Kin, const int* __restrict__ flags) {
  int n = blockIdx.x * 256 + threadIdx.x;   // 0..511
  int k = blockIdx.y;                       // 0..Kin-1
  float acc = 0.f;
  if (flags[0]) {
    const float* wr = (const float*)Ws + (size_t)k * 512;
    const float* we = (const float*)We;
#pragma unroll 8
    for (int j = 0; j < 512; ++j) acc += wr[j] * we[(size_t)j * 512 + n];
  } else {
    const short* wr = (const short*)Ws + (size_t)k * 512;
    const short* we = (const short*)We;
#pragma unroll 8
    for (int j = 0; j < 512; ++j) acc += bf2f(wr[j]) * bf2f(we[(size_t)j * 512 + n]);
  }
  VT[(size_t)n * Kin + k] = f2bf_rne(0.5f * acc);
}

// ---- per-pair column vectors: c{1,2}[n]=0.5*(b_src@W_et)[n], cb[n]=0.5*(b_et1+b_et2)[n]
__global__ void cvec_kernel(const void* __restrict__ b1s, const void* __restrict__ W1,
                            const void* __restrict__ b2s, const void* __restrict__ W2,
                            const void* __restrict__ be1, const void* __restrict__ be2,
                            float* __restrict__ c1, float* __restrict__ c2,
                            float* __restrict__ cb, const int* __restrict__ flags) {
  int n = blockIdx.x * 256 + threadIdx.x;
  float a1 = 0.f, a2 = 0.f, vb1, vb2;
  if (flags[0]) {
    const float* B1 = (const float*)b1s; const float* M1 = (const float*)W1;
    const float* B2 = (const float*)b2s; const float* M2 = (const float*)W2;
    for (int j = 0; j < 512; ++j) {
      a1 += B1[j] * M1[(size_t)j * 512 + n];
      a2 += B2[j] * M2[(size_t)j * 512 + n];
    }
    vb1 = ((const float*)be1)[n]; vb2 = ((const float*)be2)[n];
  } else {
    const short* B1 = (const short*)b1s; const short* M1 = (const short*)W1;
    const short* B2 = (const short*)b2s; const short* M2 = (const short*)W2;
    for (int j = 0; j < 512; ++j) {
      a1 += bf2f(B1[j]) * bf2f(M1[(size_t)j * 512 + n]);
      a2 += bf2f(B2[j]) * bf2f(M2[(size_t)j * 512 + n]);
    }
    vb1 = bf2f(((const short*)be1)[n]); vb2 = bf2f(((const short*)be2)[n]);
  }
  c1[n] = 0.5f * a1;
  c2[n] = 0.5f * a2;
  cb[n] = 0.5f * (vb1 + vb2);
}

// ---- pair GEMM: out[m,n] = [A1|A2]@[B1;B2] (0.5 folded into B)
//                            + s1[m]*c1[n] + s2[m]*c2[n] + cb[n]   (f32 out)
// A1:[M,512] f32, A2:[M,256] f32, B1:[512,512] bf16 (B^T rowmajor), B2:[512,256]
__global__ __launch_bounds__(256) void pair_gemm(
    const float* __restrict__ A1, const float* __restrict__ A2,
    const short* __restrict__ B1, const short* __restrict__ B2,
    const float* __restrict__ s1, const float* __restrict__ s2,
    const float* __restrict__ c1, const float* __restrict__ c2,
    const float* __restrict__ cb, float* __restrict__ out, int M) {
  __shared__ __align__(16) float lds_a[128 * 68];   // 64 f32/row + 16B pad
  __shared__ __align__(16) short lds_b[128 * 72];   // 64 bf16/row + 16B pad
  const int tid = threadIdx.x;
  const int bn = blockIdx.x, bm = blockIdx.y;
  const int m0 = bm * 128, n0 = bn * 128;
  const int lane = tid & 63, wave = tid >> 6;
  const int wm = wave & 1, wn = wave >> 1;
  const int lr = lane & 15, lq = lane >> 4;

  f32x4 acc[4][4] = {};

  for (int st = 0; st < 12; ++st) {
    const float* Ap; const short* Bp; int K, k0;
    if (st < 8) { Ap = A1; Bp = B1; K = 512; k0 = st << 6; }
    else        { Ap = A2; Bp = B2; K = 256; k0 = (st - 8) << 6; }

    // stage A: 128 rows x 17 chunks(16B) = 2176 chunks (chunk 16 of each row = pad)
#pragma unroll
    for (int i = 0; i < 9; ++i) {
      int c = tid + i * 256;
      if (c < 2176) {
        int row = c / 17;
        int cc = c - row * 17; if (cc > 15) cc = 15;   // pad chunk: harmless dup load
        int rg = m0 + row; if (rg >= M) rg = M - 1;    // clamp tail rows
        const float* gp = Ap + (size_t)rg * K + (size_t)(k0 + (cc << 2));
        __builtin_amdgcn_global_load_lds(
            (const __attribute__((address_space(1))) void*)gp,
            (__attribute__((address_space(3))) void*)(lds_a + ((size_t)c << 2)),
            16, 0, 0);
      }
    }
    // stage B: 128 rows x 9 chunks(16B) = 1152 chunks
#pragma unroll
    for (int i = 0; i < 5; ++i) {
      int c = tid + i * 256;
      if (c < 1152) {
        int row = c / 9;
        int cc = c - row * 9; if (cc > 7) cc = 7;
        const short* gp = Bp + (size_t)(n0 + row) * K + (size_t)(k0 + (cc << 3));
        __builtin_amdgcn_global_load_lds(
            (const __attribute__((address_space(1))) void*)gp,
            (__attribute__((address_space(3))) void*)(lds_b + ((size_t)c << 3)),
            16, 0, 0);
      }
    }
    __syncthreads();

#pragma unroll
    for (int ks = 0; ks < 2; ++ks) {
      short8 bfrag[4];
#pragma unroll
      for (int ni = 0; ni < 4; ++ni) {
        int nl = wn * 64 + ni * 16 + lr;
        bfrag[ni] = *(const short8*)(lds_b + nl * 72 + ks * 32 + lq * 8);
      }
#pragma unroll
      for (int mi = 0; mi < 4; ++mi) {
        int ml = wm * 64 + mi * 16 + lr;
        const float* ap = lds_a + ml * 68 + ks * 32 + lq * 8;
        int4v q0 = *(const int4v*)ap;
        int4v q1 = *(const int4v*)(ap + 4);
        // pack 8 f32 -> 8 bf16 (truncate; error sign randomized by B in the dot)
        unsigned p0 = __builtin_amdgcn_perm((unsigned)q0[1], (unsigned)q0[0], 0x07060302u);
        unsigned p1 = __builtin_amdgcn_perm((unsigned)q0[3], (unsigned)q0[2], 0x07060302u);
        unsigned p2 = __builtin_amdgcn_perm((unsigned)q1[1], (unsigned)q1[0], 0x07060302u);
        unsigned p3 = __builtin_amdgcn_perm((unsigned)q1[3], (unsigned)q1[2], 0x07060302u);
        union { int4v i; short8 s; } au;
        au.i = (int4v){(int)p0, (int)p1, (int)p2, (int)p3};
        short8 afrag = au.s;
#pragma unroll
        for (int ni = 0; ni < 4; ++ni)
          acc[mi][ni] = __builtin_amdgcn_mfma_f32_16x16x32_bf16(afrag, bfrag[ni], acc[mi][ni], 0, 0, 0);
      }
    }
    __syncthreads();
  }

  // epilogue: C/D layout col=lane&15, row=(lane>>4)*4+reg  [m89-verified]
  float ct1[4], ct2[4], ctb[4]; int gn[4];
#pragma unroll
  for (int ni = 0; ni < 4; ++ni) {
    int n = n0 + wn * 64 + ni * 16 + lr;
    gn[ni] = n; ct1[ni] = c1[n]; ct2[ni] = c2[n]; ctb[ni] = cb[n];
  }
#pragma unroll
  for (int mi = 0; mi < 4; ++mi) {
    int mb = m0 + wm * 64 + mi * 16 + (lq << 2);
#pragma unroll
    for (int r = 0; r < 4; ++r) {
      int m = mb + r;
      if (m < M) {
        float sv1 = s1[m], sv2 = s2[m];
        float* op = out + (size_t)m * 512;
#pragma unroll
        for (int ni = 0; ni < 4; ++ni)
          op[gn[ni]] = acc[mi][ni][r] + sv1 * ct1[ni] + sv2 * ct2[ni] + ctb[ni];
      }
    }
  }
}

// ---------------- workspace layout ----------------
static constexpr size_t OFF_Y_DD = 0;                                   // [ND,512] f32
static constexpr size_t OFF_Y_DG = OFF_Y_DD + (size_t)NG * 512 * 4;     // [NG,512] f32
static constexpr size_t OFF_Y_GD = OFF_Y_DG + (size_t)NG * 512 * 4;     // [ND,256] f32
static constexpr size_t OFF_Y_GG = OFF_Y_GD + (size_t)ND * 256 * 4;     // [NG,256] f32
static constexpr size_t OFF_VT_DD = OFF_Y_GG + (size_t)NG * 256 * 4;    // 512x512 bf16
static constexpr size_t OFF_VT_DG = OFF_VT_DD + 512 * 512 * 2;
static constexpr size_t OFF_VT_GD = OFF_VT_DG + 512 * 512 * 2;          // 512x256 bf16
static constexpr size_t OFF_VT_GG = OFF_VT_GD + 512 * 256 * 2;
static constexpr size_t OFF_NRM  = OFF_VT_GG + 512 * 256 * 2;           // 8 x 100000 f32
static constexpr size_t OFF_SV   = OFF_NRM + 8 * 400000;                // 4 x 100000 f32
static constexpr size_t OFF_CV   = OFF_SV + 4 * 400000;                 // 6 x 512 f32
static constexpr size_t OFF_FLG  = OFF_CV + 6 * 2048;                   // 2 x int
static constexpr size_t OFF_CSRO = OFF_FLG + 64;                        // 4 x OSTRIDE ints
static constexpr size_t OFF_CURS = OFF_CSRO + (size_t)4 * OSTRIDE * 4;  // 4 x 100000 ints
static constexpr size_t OFF_SRT  = OFF_CURS + 4 * 400000;               // 4 x (src int[NE] + w f32[NE])
static constexpr size_t OFF_PART = OFF_SRT + (size_t)4 * 2 * NE * 4;    // 4 x 512 ints
static constexpr size_t WS_NEED  = OFF_PART + 4 * 512 * 4;

extern "C" void kernel_launch(void* const* d_in, const int* in_sizes, int n_in,
                              void* d_out, int out_size, void* d_ws, size_t ws_size,
                              hipStream_t stream) {
  const void* x_d    = d_in[0];
  const void* x_g    = d_in[1];
  const void* W_drug = d_in[2];
  const void* b_drug = d_in[3];
  const void* W_gene = d_in[4];
  const void* b_gene = d_in[5];
  const void* W_dd   = d_in[6];
  const void* b_dd   = d_in[7];
  const void* W_dg   = d_in[8];
  const void* b_dg   = d_in[9];
  const void* W_gd   = d_in[10];
  const void* b_gd   = d_in[11];
  const void* W_gg   = d_in[12];
  const void* b_gg   = d_in[13];
  const int* src_dd = (const int*)d_in[14];
  const int* dst_dd = (const int*)d_in[15];
  const int* src_dg = (const int*)d_in[16];
  const int* dst_dg = (const int*)d_in[17];
  const int* src_gd = (const int*)d_in[18];
  const int* dst_gd = (const int*)d_in[19];
  const int* src_gg = (const int*)d_in[20];
  const int* dst_gg = (const int*)d_in[21];

  if (ws_size < WS_NEED) {
    fprintf(stderr, "kernel_launch: ws too small: have %zu need %zu\n", ws_size, WS_NEED);
    return;
  }

  char* ws = (char*)d_ws;
  float* y_dd = (float*)(ws + OFF_Y_DD);
  float* y_dg = (float*)(ws + OFF_Y_DG);
  float* y_gd = (float*)(ws + OFF_Y_GD);
  float* y_gg = (float*)(ws + OFF_Y_GG);
  short* vt_dd = (short*)(ws + OFF_VT_DD);
  short* vt_dg = (short*)(ws + OFF_VT_DG);
  short* vt_gd = (short*)(ws + OFF_VT_GD);
  short* vt_gg = (short*)(ws + OFF_VT_GG);
  float* degbase = (float*)(ws + OFF_NRM);
  float* ns_dd = degbase + 0 * 100000;
  float* nd_dd = degbase + 1 * 100000;
  float* ns_dg = degbase + 2 * 100000;
  float* nd_dg = degbase + 3 * 100000;
  float* ns_gd = degbase + 4 * 100000;
  float* nd_gd = degbase + 5 * 100000;
  float* ns_gg = degbase + 6 * 100000;
  float* nd_gg = degbase + 7 * 100000;
  float* s_dd = (float*)(ws + OFF_SV + 0 * 400000);
  float* s_gd = (float*)(ws + OFF_SV + 1 * 400000);
  float* s_dg = (float*)(ws + OFF_SV + 2 * 400000);
  float* s_gg = (float*)(ws + OFF_SV + 3 * 400000);
  float* c1_drug = (float*)(ws + OFF_CV + 0 * 2048);
  float* c2_drug = (float*)(ws + OFF_CV + 1 * 2048);
  float* cb_drug = (float*)(ws + OFF_CV + 2 * 2048);
  float* c1_gene = (float*)(ws + OFF_CV + 3 * 2048);
  float* c2_gene = (float*)(ws + OFF_CV + 4 * 2048);
  float* cb_gene = (float*)(ws + OFF_CV + 5 * 2048);
  int* flags = (int*)(ws + OFF_FLG);
  int* csro  = (int*)(ws + OFF_CSRO);    // + et*OSTRIDE
  int* curs  = (int*)(ws + OFF_CURS);    // + et*100000
  int* part  = (int*)(ws + OFF_PART);    // + et*512
  // sorted edge arrays per etype: srcs int[NE], weights f32[NE]
  int*   so0 = (int*)(ws + OFF_SRT + 0 * (size_t)2 * NE * 4);
  float* wo0 = (float*)(ws + OFF_SRT + 0 * (size_t)2 * NE * 4 + (size_t)NE * 4);
  int*   so1 = (int*)(ws + OFF_SRT + 1 * (size_t)2 * NE * 4);
  float* wo1 = (float*)(ws + OFF_SRT + 1 * (size_t)2 * NE * 4 + (size_t)NE * 4);
  int*   so2 = (int*)(ws + OFF_SRT + 2 * (size_t)2 * NE * 4);
  float* wo2 = (float*)(ws + OFF_SRT + 2 * (size_t)2 * NE * 4 + (size_t)NE * 4);
  int*   so3 = (int*)(ws + OFF_SRT + 3 * (size_t)2 * NE * 4);
  float* wo3 = (float*)(ws + OFF_SRT + 3 * (size_t)2 * NE * 4 + (size_t)NE * 4);

  float* out_drug = (float*)d_out;
  float* out_gene = out_drug + (size_t)ND * 512;

  // dtype detection first (independent of memsets)
  detect_kernel<<<1, 256, 0, stream>>>((const unsigned short*)x_d, src_dd, flags);

  // zero degree arrays + CSR cursors (y buffers are fully written by csr_gather now)
  hipMemsetAsync(ws + OFF_NRM, 0, 8 * 400000, stream);
  hipMemsetAsync(ws + OFF_CURS, 0, 4 * 400000, stream);

  // degrees (deg_out over src, deg_in over dst)
  dim3 hb((NE + 255) / 256);
  hist_kernel<<<hb, 256, 0, stream>>>(src_dd, ns_dd, flags);
  hist_kernel<<<hb, 256, 0, stream>>>(dst_dd, nd_dd, flags);
  hist_kernel<<<hb, 256, 0, stream>>>(src_dg, ns_dg, flags);
  hist_kernel<<<hb, 256, 0, stream>>>(dst_dg, nd_dg, flags);
  hist_kernel<<<hb, 256, 0, stream>>>(src_gd, ns_gd, flags);
  hist_kernel<<<hb, 256, 0, stream>>>(dst_gd, nd_gd, flags);
  hist_kernel<<<hb, 256, 0, stream>>>(src_gg, ns_gg, flags);
  hist_kernel<<<hb, 256, 0, stream>>>(dst_gg, nd_gg, flags);

  // CSR offsets from raw dst degrees (must run BEFORE norm_kernel overwrites them)
  scan_partial<<<dim3(NB, 4), 256, 0, stream>>>(degbase, part);
  scan_single<<<4, 512, 0, stream>>>(part);
  scan_final<<<dim3(NB, 4), 256, 0, stream>>>(degbase, part, csro);

  // in-place deg -> rsqrt(max(deg,1)) over all 8 arrays
  norm_kernel<<<(800000 + 255) / 256, 256, 0, stream>>>(ns_dd, 800000);

  // combined weights V^T = 0.5*(W_src @ W_et)^T  and bias column vectors
  vt_kernel<<<dim3(2, 512), 256, 0, stream>>>(W_drug, W_dd, vt_dd, 512, flags);
  vt_kernel<<<dim3(2, 512), 256, 0, stream>>>(W_drug, W_dg, vt_dg, 512, flags);
  vt_kernel<<<dim3(2, 256), 256, 0, stream>>>(W_gene, W_gd, vt_gd, 256, flags);
  vt_kernel<<<dim3(2, 256), 256, 0, stream>>>(W_gene, W_gg, vt_gg, 256, flags);
  cvec_kernel<<<2, 256, 0, stream>>>(b_drug, W_dd, b_gene, W_gd, b_dd, b_gd,
                                     c1_drug, c2_drug, cb_drug, flags);
  cvec_kernel<<<2, 256, 0, stream>>>(b_drug, W_dg, b_gene, W_gg, b_dg, b_gg,
                                     c1_gene, c2_gene, cb_gene, flags);

  // build dst-sorted edge lists (needs normalized ns)
  dim3 sb((NE + 255) / 256);
  csr_scatter<<<sb, 256, 0, stream>>>(src_dd, dst_dd, ns_dd, csro + 0 * OSTRIDE,
                                      curs + 0 * 100000, so0, wo0, flags);
  csr_scatter<<<sb, 256, 0, stream>>>(src_dg, dst_dg, ns_dg, csro + 1 * OSTRIDE,
                                      curs + 1 * 100000, so1, wo1, flags);
  csr_scatter<<<sb, 256, 0, stream>>>(src_gd, dst_gd, ns_gd, csro + 2 * OSTRIDE,
                                      curs + 2 * 100000, so2, wo2, flags);
  csr_scatter<<<sb, 256, 0, stream>>>(src_gg, dst_gg, ns_gg, csro + 3 * OSTRIDE,
                                      curs + 3 * 100000, so3, wo3, flags);

  // per-destination gather-aggregate (no atomics): y[d] = nd[d]*sum_e ns[s]*x[s], s[d] = nd[d]*sum_e ns[s]
  dim3 gb(NNODE / 4);
  csr_gather<8><<<gb, 256, 0, stream>>>(x_d, csro + 0 * OSTRIDE, so0, wo0, nd_dd, y_dd, s_dd, flags);
  csr_gather<8><<<gb, 256, 0, stream>>>(x_d, csro + 1 * OSTRIDE, so1, wo1, nd_dg, y_dg, s_dg, flags);
  csr_gather<4><<<gb, 256, 0, stream>>>(x_g, csro + 2 * OSTRIDE, so2, wo2, nd_gd, y_gd, s_gd, flags);
  csr_gather<4><<<gb, 256, 0, stream>>>(x_g, csro + 3 * OSTRIDE, so3, wo3, nd_gg, y_gg, s_gg, flags);

  // fused pair GEMMs -> f32 outputs
  dim3 gg(4, (ND + 127) / 128);
  pair_gemm<<<gg, 256, 0, stream>>>(y_dd, y_gd, vt_dd, vt_gd, s_dd, s_gd,
                                    c1_drug, c2_drug, cb_drug, out_drug, ND);
  pair_gemm<<<gg, 256, 0, stream>>>(y_dg, y_gg, vt_dg, vt_gg, s_dg, s_gg,
                                    c1_gene, c2_gene, cb_gene, out_gene, NG);
}

// Round 4
// 1471.641 us; speedup vs baseline: 7.8396x; 1.1575x over previous
//
#include <hip/hip_runtime.h>
#include <stdint.h>
#include <stdio.h>

#define ND 100000
#define NG 100000
#define NE 250000
#define NNODE 100000
#define NB 391          // ceil(NNODE/256)
#define NBE 977         // ceil(NE/256)
#define OSTRIDE 100016  // ints per etype in the CSR-offsets region

typedef __attribute__((ext_vector_type(8))) short short8;
typedef __attribute__((ext_vector_type(4))) int   int4v;
typedef __attribute__((ext_vector_type(2))) int   int2v;
typedef __attribute__((ext_vector_type(4))) float f32x4;

__device__ __forceinline__ float bf2f(short s) {
  union { unsigned u; float f; } v;
  v.u = ((unsigned)(unsigned short)s) << 16;
  return v.f;
}
__device__ __forceinline__ short f2bf_rne(float f) {
  union { float f; unsigned u; } v;
  v.f = f;
  unsigned u = v.u + 0x7FFFu + ((v.u >> 16) & 1u);
  return (short)(u >> 16);
}

// ---- dtype detection: flags[0]=features are f32, flags[1]=indices are int64 ----
__global__ void detect_kernel(const unsigned short* __restrict__ xs,
                              const int* __restrict__ idx, int* __restrict__ flags) {
  __shared__ int cnt_huge, cnt_oddnz;
  if (threadIdx.x == 0) { cnt_huge = 0; cnt_oddnz = 0; }
  __syncthreads();
  int t = threadIdx.x;
  int h = 0;
#pragma unroll
  for (int i = 0; i < 8; ++i) {
    unsigned e = ((unsigned)xs[t * 8 + i] >> 7) & 0xFFu;
    if (e >= 0xC0u) ++h;  // |v| >= 2^65 or Inf/NaN: impossible for N(0,1) bf16 data
  }
  if (h) atomicAdd(&cnt_huge, h);
  if (t < 128 && idx[2 * t + 1] != 0) atomicAdd(&cnt_oddnz, 1);
  __syncthreads();
  if (t == 0) {
    flags[0] = (cnt_huge > 8) ? 1 : 0;
    flags[1] = (cnt_oddnz == 0) ? 1 : 0;  // int64: odd words all zero (values < 2^31)
  }
}

// ---- merged degree histograms: slot y in [0,8), deg[slot][idx[e]] += 1 ----
__global__ void hist8_kernel(const int* __restrict__ i0, const int* __restrict__ i1,
                             const int* __restrict__ i2, const int* __restrict__ i3,
                             const int* __restrict__ i4, const int* __restrict__ i5,
                             const int* __restrict__ i6, const int* __restrict__ i7,
                             float* __restrict__ degbase, const int* __restrict__ flags) {
  int slot = blockIdx.y;
  const int* idx = slot == 0 ? i0 : slot == 1 ? i1 : slot == 2 ? i2 : slot == 3 ? i3
                 : slot == 4 ? i4 : slot == 5 ? i5 : slot == 6 ? i6 : i7;
  int t = blockIdx.x * blockDim.x + threadIdx.x;
  if (t < NE) {
    int v = flags[1] ? idx[2 * (size_t)t] : idx[t];
    atomicAdd(degbase + (size_t)slot * NNODE + v, 1.0f);
  }
}

// ---- in-place deg -> rsqrt(max(deg,1)) ----
__global__ void norm_kernel(float* __restrict__ d, int n) {
  int t = blockIdx.x * blockDim.x + threadIdx.x;
  if (t < n) {
    float v = d[t];
    d[t] = rsqrtf(v < 1.0f ? 1.0f : v);
  }
}

// ============ CSR build: 3-kernel exclusive scan over dst degrees + scatter ============
// dst-degree array for etype et lives at degbase + (2*et+1)*NNODE.

__global__ void scan_partial(const float* __restrict__ degbase, int* __restrict__ part) {
  int et = blockIdx.y, t = threadIdx.x;
  const float* deg = degbase + (size_t)(2 * et + 1) * NNODE;
  __shared__ int sm[256];
  int i = blockIdx.x * 256 + t;
  int v = (i < NNODE) ? (int)deg[i] : 0;
  sm[t] = v;
  __syncthreads();
  for (int s = 128; s > 0; s >>= 1) {
    if (t < s) sm[t] += sm[t + s];
    __syncthreads();
  }
  if (t == 0) part[et * 512 + blockIdx.x] = sm[0];
}

__global__ void scan_single(int* __restrict__ part) {
  int et = blockIdx.x, t = threadIdx.x;
  __shared__ int sm[512];
  int v = (t < NB) ? part[et * 512 + t] : 0;
  sm[t] = v;
  __syncthreads();
  for (int s = 1; s < 512; s <<= 1) {
    int a = (t >= s) ? sm[t - s] : 0;
    __syncthreads();
    sm[t] += a;
    __syncthreads();
  }
  if (t < NB) part[et * 512 + t] = sm[t] - v;  // exclusive
}

__global__ void scan_final(const float* __restrict__ degbase, const int* __restrict__ part,
                           int* __restrict__ offsbase) {
  int et = blockIdx.y, t = threadIdx.x;
  const float* deg = degbase + (size_t)(2 * et + 1) * NNODE;
  int* offs = offsbase + (size_t)et * OSTRIDE;
  __shared__ int sm[256];
  int i = blockIdx.x * 256 + t;
  int v = (i < NNODE) ? (int)deg[i] : 0;
  sm[t] = v;
  __syncthreads();
  for (int s = 1; s < 256; s <<= 1) {
    int a = (t >= s) ? sm[t - s] : 0;
    __syncthreads();
    sm[t] += a;
    __syncthreads();
  }
  int excl = sm[t] - v;
  int base = part[et * 512 + blockIdx.x];
  if (i < NNODE) offs[i] = base + excl;
  if (i == NNODE - 1) offs[NNODE] = base + excl + v;  // == NE
}

// ---- scatter edges into dst-CSR as interleaved (src, ns[src]) 8B records ----
__global__ void csr_scatter4(
    const int* __restrict__ s0, const int* __restrict__ d0,
    const int* __restrict__ s1, const int* __restrict__ d1,
    const int* __restrict__ s2, const int* __restrict__ d2,
    const int* __restrict__ s3, const int* __restrict__ d3,
    const float* __restrict__ degbase, const int* __restrict__ csro,
    int* __restrict__ curs, int* __restrict__ ewbase, const int* __restrict__ flags) {
  int et = blockIdx.y;
  const int* src = et == 0 ? s0 : et == 1 ? s1 : et == 2 ? s2 : s3;
  const int* dst = et == 0 ? d0 : et == 1 ? d1 : et == 2 ? d2 : d3;
  const float* ns = degbase + (size_t)(2 * et) * NNODE;
  const int* offs = csro + (size_t)et * OSTRIDE;
  int* cur = curs + (size_t)et * NNODE;
  int* ew = ewbase + (size_t)et * 2 * NE;
  int t = blockIdx.x * blockDim.x + threadIdx.x;
  if (t >= NE) return;
  int i64 = flags[1];
  int s = i64 ? src[2 * (size_t)t] : src[t];
  int d = i64 ? dst[2 * (size_t)t] : dst[t];
  int pos = offs[d] + atomicAdd(&cur[d], 1);
  union { float f; int i; } u;
  u.f = ns[s];
  int2v v; v[0] = s; v[1] = u.i;
  *(int2v*)(ew + 2 * (size_t)pos) = v;
}

// ---- one x-row FMA into the wave's accumulator ----
template <int EL>
__device__ __forceinline__ void accum_row(const void* __restrict__ x, int s, float w,
                                          float* acc, int lane, int xf) {
  constexpr int D = EL * 64;
  if (xf) {
    const float* xp = (const float*)x + (size_t)s * D + lane * EL;
    if constexpr (EL == 8) {
      f32x4 q0 = *(const f32x4*)xp;
      f32x4 q1 = *(const f32x4*)(xp + 4);
#pragma unroll
      for (int i = 0; i < 4; ++i) { acc[i] += w * q0[i]; acc[4 + i] += w * q1[i]; }
    } else {
      f32x4 q0 = *(const f32x4*)xp;
#pragma unroll
      for (int i = 0; i < 4; ++i) acc[i] += w * q0[i];
    }
  } else {
    const short* xp = (const short*)x + (size_t)s * D + lane * EL;
    if constexpr (EL == 8) {
      int4v q = *(const int4v*)xp;
#pragma unroll
      for (int i = 0; i < 4; ++i) {
        unsigned u = (unsigned)q[i];
        union { unsigned u; float f; } lo, hi;
        lo.u = u << 16; hi.u = u & 0xFFFF0000u;
        acc[2 * i] += w * lo.f;
        acc[2 * i + 1] += w * hi.f;
      }
    } else {
      int2v q = *(const int2v*)(xp);
#pragma unroll
      for (int i = 0; i < 2; ++i) {
        unsigned u = (unsigned)q[i];
        union { unsigned u; float f; } lo, hi;
        lo.u = u << 16; hi.u = u & 0xFFFF0000u;
        acc[2 * i] += w * lo.f;
        acc[2 * i + 1] += w * hi.f;
      }
    }
  }
}

// ---- per-destination gather-aggregate, two etypes sharing one x, interleaved by
//      block parity for L3 temporal reuse. bf16-rne output, non-temporal stores. ----
template <int EL>
__global__ __launch_bounds__(256) void csr_gather2(
    const void* __restrict__ x,
    const int* __restrict__ offsA, const int* __restrict__ ewA,
    const float* __restrict__ ndA, short* __restrict__ yA, float* __restrict__ svA,
    const int* __restrict__ offsB, const int* __restrict__ ewB,
    const float* __restrict__ ndB, short* __restrict__ yB, float* __restrict__ svB,
    const int* __restrict__ flags) {
  constexpr int D = EL * 64;
  int which = blockIdx.x & 1;
  int d = (blockIdx.x >> 1) * 4 + (threadIdx.x >> 6);
  int lane = threadIdx.x & 63;
  int xf = flags[0];
  const int* offs = which ? offsB : offsA;
  const int* ew   = which ? ewB : ewA;
  const float* nd = which ? ndB : ndA;
  short* y        = which ? yB : yA;
  float* sv       = which ? svB : svA;

  int beg = offs[d], end = offs[d + 1];
  float acc[EL];
#pragma unroll
  for (int i = 0; i < EL; ++i) acc[i] = 0.f;
  float sw = 0.f;
  int j = beg;
  for (; j + 2 <= end; j += 2) {
    int2v e0 = *(const int2v*)(ew + 2 * (size_t)j);
    int2v e1 = *(const int2v*)(ew + 2 * (size_t)j + 2);
    union { int i; float f; } u0, u1;
    u0.i = e0[1]; u1.i = e1[1];
    sw += u0.f + u1.f;
    accum_row<EL>(x, e0[0], u0.f, acc, lane, xf);
    accum_row<EL>(x, e1[0], u1.f, acc, lane, xf);
  }
  if (j < end) {
    int2v e0 = *(const int2v*)(ew + 2 * (size_t)j);
    union { int i; float f; } u0;
    u0.i = e0[1];
    sw += u0.f;
    accum_row<EL>(x, e0[0], u0.f, acc, lane, xf);
  }
  float ndv = nd[d];
  if constexpr (EL == 8) {
    union { short s[8]; int4v v; } o;
#pragma unroll
    for (int i = 0; i < 8; ++i) o.s[i] = f2bf_rne(acc[i] * ndv);
    __builtin_nontemporal_store(o.v, (int4v*)(y + (size_t)d * D + lane * EL));
  } else {
    union { short s[4]; int2v v; } o;
#pragma unroll
    for (int i = 0; i < 4; ++i) o.s[i] = f2bf_rne(acc[i] * ndv);
    __builtin_nontemporal_store(o.v, (int2v*)(y + (size_t)d * D + lane * EL));
  }
  if (lane == 0) sv[d] = ndv * sw;
}

// ---- VT[n,k] = 0.5 * sum_j Ws[k,j] * We[j,n]   (V = Ws@We, stored transposed, bf16)
__global__ void vt_kernel(const void* __restrict__ Ws, const void* __restrict__ We,
                          short* __restrict__ VT, int Kin, const int* __restrict__ flags) {
  int n = blockIdx.x * 256 + threadIdx.x;   // 0..511
  int k = blockIdx.y;                       // 0..Kin-1
  float acc = 0.f;
  if (flags[0]) {
    const float* wr = (const float*)Ws + (size_t)k * 512;
    const float* we = (const float*)We;
#pragma unroll 8
    for (int j = 0; j < 512; ++j) acc += wr[j] * we[(size_t)j * 512 + n];
  } else {
    const short* wr = (const short*)Ws + (size_t)k * 512;
    const short* we = (const short*)We;
#pragma unroll 8
    for (int j = 0; j < 512; ++j) acc += bf2f(wr[j]) * bf2f(we[(size_t)j * 512 + n]);
  }
  VT[(size_t)n * Kin + k] = f2bf_rne(0.5f * acc);
}

// ---- per-pair column vectors: c{1,2}[n]=0.5*(b_src@W_et)[n], cb[n]=0.5*(b_et1+b_et2)[n]
__global__ void cvec_kernel(const void* __restrict__ b1s, const void* __restrict__ W1,
                            const void* __restrict__ b2s, const void* __restrict__ W2,
                            const void* __restrict__ be1, const void* __restrict__ be2,
                            float* __restrict__ c1, float* __restrict__ c2,
                            float* __restrict__ cb, const int* __restrict__ flags) {
  int n = blockIdx.x * 256 + threadIdx.x;
  float a1 = 0.f, a2 = 0.f, vb1, vb2;
  if (flags[0]) {
    const float* B1 = (const float*)b1s; const float* M1 = (const float*)W1;
    const float* B2 = (const float*)b2s; const float* M2 = (const float*)W2;
    for (int j = 0; j < 512; ++j) {
      a1 += B1[j] * M1[(size_t)j * 512 + n];
      a2 += B2[j] * M2[(size_t)j * 512 + n];
    }
    vb1 = ((const float*)be1)[n]; vb2 = ((const float*)be2)[n];
  } else {
    const short* B1 = (const short*)b1s; const short* M1 = (const short*)W1;
    const short* B2 = (const short*)b2s; const short* M2 = (const short*)W2;
    for (int j = 0; j < 512; ++j) {
      a1 += bf2f(B1[j]) * bf2f(M1[(size_t)j * 512 + n]);
      a2 += bf2f(B2[j]) * bf2f(M2[(size_t)j * 512 + n]);
    }
    vb1 = bf2f(((const short*)be1)[n]); vb2 = bf2f(((const short*)be2)[n]);
  }
  c1[n] = 0.5f * a1;
  c2[n] = 0.5f * a2;
  cb[n] = 0.5f * (vb1 + vb2);
}

// ---- pair GEMM: out[m,n] = [A1|A2]@[B1;B2] (0.5 folded into B)
//                            + s1[m]*c1[n] + s2[m]*c2[n] + cb[n]   (f32 out)
// A1:[M,512] bf16, A2:[M,256] bf16, B1:[512,512] bf16 (B^T rowmajor), B2:[512,256]
__global__ __launch_bounds__(256) void pair_gemm(
    const short* __restrict__ A1, const short* __restrict__ A2,
    const short* __restrict__ B1, const short* __restrict__ B2,
    const float* __restrict__ s1, const float* __restrict__ s2,
    const float* __restrict__ c1, const float* __restrict__ c2,
    const float* __restrict__ cb, float* __restrict__ out, int M) {
  __shared__ __align__(16) short lds_a[128 * 72];   // 64 bf16/row + 16B pad
  __shared__ __align__(16) short lds_b[128 * 72];
  const int tid = threadIdx.x;
  const int bn = blockIdx.x, bm = blockIdx.y;
  const int m0 = bm * 128, n0 = bn * 128;
  const int lane = tid & 63, wave = tid >> 6;
  const int wm = wave & 1, wn = wave >> 1;
  const int lr = lane & 15, lq = lane >> 4;

  f32x4 acc[4][4] = {};

  for (int st = 0; st < 12; ++st) {
    const short* Ap; const short* Bp; int K, k0;
    if (st < 8) { Ap = A1; Bp = B1; K = 512; k0 = st << 6; }
    else        { Ap = A2; Bp = B2; K = 256; k0 = (st - 8) << 6; }

    // stage A: 128 rows x 9 chunks(16B) = 1152 chunks (chunk 8 of each row = pad)
#pragma unroll
    for (int i = 0; i < 5; ++i) {
      int c = tid + i * 256;
      if (c < 1152) {
        int row = c / 9;
        int cc = c - row * 9; if (cc > 7) cc = 7;   // pad chunk: harmless dup load
        int rg = m0 + row; if (rg >= M) rg = M - 1; // clamp tail rows
        const short* gp = Ap + (size_t)rg * K + (size_t)(k0 + (cc << 3));
        __builtin_amdgcn_global_load_lds(
            (const __attribute__((address_space(1))) void*)gp,
            (__attribute__((address_space(3))) void*)(lds_a + ((size_t)c << 3)),
            16, 0, 0);
      }
    }
    // stage B: 128 rows x 9 chunks(16B) = 1152 chunks
#pragma unroll
    for (int i = 0; i < 5; ++i) {
      int c = tid + i * 256;
      if (c < 1152) {
        int row = c / 9;
        int cc = c - row * 9; if (cc > 7) cc = 7;
        const short* gp = Bp + (size_t)(n0 + row) * K + (size_t)(k0 + (cc << 3));
        __builtin_amdgcn_global_load_lds(
            (const __attribute__((address_space(1))) void*)gp,
            (__attribute__((address_space(3))) void*)(lds_b + ((size_t)c << 3)),
            16, 0, 0);
      }
    }
    __syncthreads();

#pragma unroll
    for (int ks = 0; ks < 2; ++ks) {
      short8 bfrag[4];
#pragma unroll
      for (int ni = 0; ni < 4; ++ni) {
        int nl = wn * 64 + ni * 16 + lr;
        bfrag[ni] = *(const short8*)(lds_b + nl * 72 + ks * 32 + lq * 8);
      }
#pragma unroll
      for (int mi = 0; mi < 4; ++mi) {
        int ml = wm * 64 + mi * 16 + lr;
        short8 afrag = *(const short8*)(lds_a + ml * 72 + ks * 32 + lq * 8);
#pragma unroll
        for (int ni = 0; ni < 4; ++ni)
          acc[mi][ni] = __builtin_amdgcn_mfma_f32_16x16x32_bf16(afrag, bfrag[ni], acc[mi][ni], 0, 0, 0);
      }
    }
    __syncthreads();
  }

  // epilogue: C/D layout col=lane&15, row=(lane>>4)*4+reg  [m89-verified]
  float ct1[4], ct2[4], ctb[4]; int gn[4];
#pragma unroll
  for (int ni = 0; ni < 4; ++ni) {
    int n = n0 + wn * 64 + ni * 16 + lr;
    gn[ni] = n; ct1[ni] = c1[n]; ct2[ni] = c2[n]; ctb[ni] = cb[n];
  }
#pragma unroll
  for (int mi = 0; mi < 4; ++mi) {
    int mb = m0 + wm * 64 + mi * 16 + (lq << 2);
#pragma unroll
    for (int r = 0; r < 4; ++r) {
      int m = mb + r;
      if (m < M) {
        float sv1 = s1[m], sv2 = s2[m];
        float* op = out + (size_t)m * 512;
#pragma unroll
        for (int ni = 0; ni < 4; ++ni)
          __builtin_nontemporal_store(
              acc[mi][ni][r] + sv1 * ct1[ni] + sv2 * ct2[ni] + ctb[ni], op + gn[ni]);
      }
    }
  }
}

// ---------------- workspace layout ----------------
static constexpr size_t OFF_Y_DD = 0;                                    // [ND,512] bf16
static constexpr size_t OFF_Y_DG = OFF_Y_DD + (size_t)NNODE * 512 * 2;   // [NG,512] bf16
static constexpr size_t OFF_Y_GD = OFF_Y_DG + (size_t)NNODE * 512 * 2;   // [ND,256] bf16
static constexpr size_t OFF_Y_GG = OFF_Y_GD + (size_t)NNODE * 256 * 2;   // [NG,256] bf16
static constexpr size_t OFF_VT_DD = OFF_Y_GG + (size_t)NNODE * 256 * 2;  // 512x512 bf16
static constexpr size_t OFF_VT_DG = OFF_VT_DD + 512 * 512 * 2;
static constexpr size_t OFF_VT_GD = OFF_VT_DG + 512 * 512 * 2;           // 512x256 bf16
static constexpr size_t OFF_VT_GG = OFF_VT_GD + 512 * 256 * 2;
static constexpr size_t OFF_NRM  = OFF_VT_GG + 512 * 256 * 2;            // 8 x 100000 f32
static constexpr size_t OFF_SV   = OFF_NRM + 8 * 400000;                 // 4 x 100000 f32
static constexpr size_t OFF_CV   = OFF_SV + 4 * 400000;                  // 6 x 512 f32
static constexpr size_t OFF_FLG  = OFF_CV + 6 * 2048;                    // 2 x int
static constexpr size_t OFF_CSRO = OFF_FLG + 64;                         // 4 x OSTRIDE ints
static constexpr size_t OFF_CURS = OFF_CSRO + (size_t)4 * OSTRIDE * 4;   // 4 x 100000 ints
static constexpr size_t OFF_SRT  = OFF_CURS + 4 * 400000;                // 4 x NE x 8B (src,w)
static constexpr size_t OFF_PART = OFF_SRT + (size_t)4 * 2 * NE * 4;     // 4 x 512 ints
static constexpr size_t WS_NEED  = OFF_PART + 4 * 512 * 4;

extern "C" void kernel_launch(void* const* d_in, const int* in_sizes, int n_in,
                              void* d_out, int out_size, void* d_ws, size_t ws_size,
                              hipStream_t stream) {
  const void* x_d    = d_in[0];
  const void* x_g    = d_in[1];
  const void* W_drug = d_in[2];
  const void* b_drug = d_in[3];
  const void* W_gene = d_in[4];
  const void* b_gene = d_in[5];
  const void* W_dd   = d_in[6];
  const void* b_dd   = d_in[7];
  const void* W_dg   = d_in[8];
  const void* b_dg   = d_in[9];
  const void* W_gd   = d_in[10];
  const void* b_gd   = d_in[11];
  const void* W_gg   = d_in[12];
  const void* b_gg   = d_in[13];
  const int* src_dd = (const int*)d_in[14];
  const int* dst_dd = (const int*)d_in[15];
  const int* src_dg = (const int*)d_in[16];
  const int* dst_dg = (const int*)d_in[17];
  const int* src_gd = (const int*)d_in[18];
  const int* dst_gd = (const int*)d_in[19];
  const int* src_gg = (const int*)d_in[20];
  const int* dst_gg = (const int*)d_in[21];

  if (ws_size < WS_NEED) {
    fprintf(stderr, "kernel_launch: ws too small: have %zu need %zu\n", ws_size, WS_NEED);
    return;
  }

  char* ws = (char*)d_ws;
  short* y_dd = (short*)(ws + OFF_Y_DD);
  short* y_dg = (short*)(ws + OFF_Y_DG);
  short* y_gd = (short*)(ws + OFF_Y_GD);
  short* y_gg = (short*)(ws + OFF_Y_GG);
  short* vt_dd = (short*)(ws + OFF_VT_DD);
  short* vt_dg = (short*)(ws + OFF_VT_DG);
  short* vt_gd = (short*)(ws + OFF_VT_GD);
  short* vt_gg = (short*)(ws + OFF_VT_GG);
  float* degbase = (float*)(ws + OFF_NRM);
  float* nd_dd = degbase + 1 * NNODE;
  float* nd_dg = degbase + 3 * NNODE;
  float* nd_gd = degbase + 5 * NNODE;
  float* nd_gg = degbase + 7 * NNODE;
  float* s_dd = (float*)(ws + OFF_SV + 0 * 400000);
  float* s_gd = (float*)(ws + OFF_SV + 1 * 400000);
  float* s_dg = (float*)(ws + OFF_SV + 2 * 400000);
  float* s_gg = (float*)(ws + OFF_SV + 3 * 400000);
  float* c1_drug = (float*)(ws + OFF_CV + 0 * 2048);
  float* c2_drug = (float*)(ws + OFF_CV + 1 * 2048);
  float* cb_drug = (float*)(ws + OFF_CV + 2 * 2048);
  float* c1_gene = (float*)(ws + OFF_CV + 3 * 2048);
  float* c2_gene = (float*)(ws + OFF_CV + 4 * 2048);
  float* cb_gene = (float*)(ws + OFF_CV + 5 * 2048);
  int* flags = (int*)(ws + OFF_FLG);
  int* csro  = (int*)(ws + OFF_CSRO);    // + et*OSTRIDE
  int* curs  = (int*)(ws + OFF_CURS);    // + et*NNODE
  int* ewbase = (int*)(ws + OFF_SRT);    // + et*2*NE
  int* part  = (int*)(ws + OFF_PART);    // + et*512

  float* out_drug = (float*)d_out;
  float* out_gene = out_drug + (size_t)ND * 512;

  // dtype detection first (independent of memsets)
  detect_kernel<<<1, 256, 0, stream>>>((const unsigned short*)x_d, src_dd, flags);

  // zero degree arrays + CSR cursors (y buffers are fully written by csr_gather2)
  hipMemsetAsync(ws + OFF_NRM, 0, 8 * 400000, stream);
  hipMemsetAsync(ws + OFF_CURS, 0, 4 * 400000, stream);

  // degrees: slots 0..7 = ns_dd,nd_dd,ns_dg,nd_dg,ns_gd,nd_gd,ns_gg,nd_gg
  hist8_kernel<<<dim3(NBE, 8), 256, 0, stream>>>(
      src_dd, dst_dd, src_dg, dst_dg, src_gd, dst_gd, src_gg, dst_gg, degbase, flags);

  // CSR offsets from raw dst degrees (must run BEFORE norm_kernel overwrites them)
  scan_partial<<<dim3(NB, 4), 256, 0, stream>>>(degbase, part);
  scan_single<<<4, 512, 0, stream>>>(part);
  scan_final<<<dim3(NB, 4), 256, 0, stream>>>(degbase, part, csro);

  // in-place deg -> rsqrt(max(deg,1)) over all 8 arrays
  norm_kernel<<<(800000 + 255) / 256, 256, 0, stream>>>(degbase, 800000);

  // combined weights V^T = 0.5*(W_src @ W_et)^T  and bias column vectors
  vt_kernel<<<dim3(2, 512), 256, 0, stream>>>(W_drug, W_dd, vt_dd, 512, flags);
  vt_kernel<<<dim3(2, 512), 256, 0, stream>>>(W_drug, W_dg, vt_dg, 512, flags);
  vt_kernel<<<dim3(2, 256), 256, 0, stream>>>(W_gene, W_gd, vt_gd, 256, flags);
  vt_kernel<<<dim3(2, 256), 256, 0, stream>>>(W_gene, W_gg, vt_gg, 256, flags);
  cvec_kernel<<<2, 256, 0, stream>>>(b_drug, W_dd, b_gene, W_gd, b_dd, b_gd,
                                     c1_drug, c2_drug, cb_drug, flags);
  cvec_kernel<<<2, 256, 0, stream>>>(b_drug, W_dg, b_gene, W_gg, b_dg, b_gg,
                                     c1_gene, c2_gene, cb_gene, flags);

  // build dst-sorted (src, ns[src]) edge records (needs normalized ns)
  csr_scatter4<<<dim3(NBE, 4), 256, 0, stream>>>(
      src_dd, dst_dd, src_dg, dst_dg, src_gd, dst_gd, src_gg, dst_gg,
      degbase, csro, curs, ewbase, flags);

  // gather-aggregate, etype pairs sharing x interleaved for L3 reuse
  dim3 gb(2 * (NNODE / 4));
  csr_gather2<8><<<gb, 256, 0, stream>>>(
      x_d, csro + 0 * OSTRIDE, ewbase + 0 * 2 * NE, nd_dd, y_dd, s_dd,
           csro + 1 * OSTRIDE, ewbase + 1 * 2 * NE, nd_dg, y_dg, s_dg, flags);
  csr_gather2<4><<<gb, 256, 0, stream>>>(
      x_g, csro + 2 * OSTRIDE, ewbase + 2 * 2 * NE, nd_gd, y_gd, s_gd,
           csro + 3 * OSTRIDE, ewbase + 3 * 2 * NE, nd_gg, y_gg, s_gg, flags);

  // fused pair GEMMs -> f32 outputs
  dim3 gg(4, (ND + 127) / 128);
  pair_gemm<<<gg, 256, 0, stream>>>(y_dd, y_gd, vt_dd, vt_gd, s_dd, s_gd,
                                    c1_drug, c2_drug, cb_drug, out_drug, ND);
  pair_gemm<<<gg, 256, 0, stream>>>(y_dg, y_gg, vt_dg, vt_gg, s_dg, s_gg,
                                    c1_gene, c2_gene, cb_gene, out_gene, NG);
}

// Round 5
// 1452.636 us; speedup vs baseline: 7.9422x; 1.0131x over previous
//
#include <hip/hip_runtime.h>
#include <stdint.h>
#include <stdio.h>

#define ND 100000
#define NG 100000
#define NE 250000
#define NNODE 100000
#define NB 391          // ceil(NNODE/256)
#define NBE 977         // ceil(NE/256)
#define OSTRIDE 100016  // ints per etype in the CSR-offsets region

typedef __attribute__((ext_vector_type(8))) short short8;
typedef __attribute__((ext_vector_type(4))) int   int4v;
typedef __attribute__((ext_vector_type(2))) int   int2v;
typedef __attribute__((ext_vector_type(4))) float f32x4;

__device__ __forceinline__ float bf2f(short s) {
  union { unsigned u; float f; } v;
  v.u = ((unsigned)(unsigned short)s) << 16;
  return v.f;
}
__device__ __forceinline__ short f2bf_rne(float f) {
  union { float f; unsigned u; } v;
  v.f = f;
  unsigned u = v.u + 0x7FFFu + ((v.u >> 16) & 1u);
  return (short)(u >> 16);
}

// ---- dtype detection: flags[0]=features are f32, flags[1]=indices are int64 ----
__global__ void detect_kernel(const unsigned short* __restrict__ xs,
                              const int* __restrict__ idx, int* __restrict__ flags) {
  __shared__ int cnt_huge, cnt_oddnz;
  if (threadIdx.x == 0) { cnt_huge = 0; cnt_oddnz = 0; }
  __syncthreads();
  int t = threadIdx.x;
  int h = 0;
#pragma unroll
  for (int i = 0; i < 8; ++i) {
    unsigned e = ((unsigned)xs[t * 8 + i] >> 7) & 0xFFu;
    if (e >= 0xC0u) ++h;  // |v| >= 2^65 or Inf/NaN: impossible for N(0,1) bf16 data
  }
  if (h) atomicAdd(&cnt_huge, h);
  if (t < 128 && idx[2 * t + 1] != 0) atomicAdd(&cnt_oddnz, 1);
  __syncthreads();
  if (t == 0) {
    flags[0] = (cnt_huge > 8) ? 1 : 0;
    flags[1] = (cnt_oddnz == 0) ? 1 : 0;  // int64: odd words all zero (values < 2^31)
  }
}

// ---- merged degree histograms: slot y in [0,8), deg[slot][idx[e]] += 1 ----
__global__ void hist8_kernel(const int* __restrict__ i0, const int* __restrict__ i1,
                             const int* __restrict__ i2, const int* __restrict__ i3,
                             const int* __restrict__ i4, const int* __restrict__ i5,
                             const int* __restrict__ i6, const int* __restrict__ i7,
                             float* __restrict__ degbase, const int* __restrict__ flags) {
  int slot = blockIdx.y;
  const int* idx = slot == 0 ? i0 : slot == 1 ? i1 : slot == 2 ? i2 : slot == 3 ? i3
                 : slot == 4 ? i4 : slot == 5 ? i5 : slot == 6 ? i6 : i7;
  int t = blockIdx.x * blockDim.x + threadIdx.x;
  if (t < NE) {
    int v = flags[1] ? idx[2 * (size_t)t] : idx[t];
    atomicAdd(degbase + (size_t)slot * NNODE + v, 1.0f);
  }
}

// ============ CSR build: 3-kernel exclusive scan over dst degrees + scatter ============
// dst-degree array for etype et lives at degbase + (2*et+1)*NNODE (RAW counts).

__global__ void scan_partial(const float* __restrict__ degbase, int* __restrict__ part) {
  int et = blockIdx.y, t = threadIdx.x;
  const float* deg = degbase + (size_t)(2 * et + 1) * NNODE;
  __shared__ int sm[256];
  int i = blockIdx.x * 256 + t;
  int v = (i < NNODE) ? (int)deg[i] : 0;
  sm[t] = v;
  __syncthreads();
  for (int s = 128; s > 0; s >>= 1) {
    if (t < s) sm[t] += sm[t + s];
    __syncthreads();
  }
  if (t == 0) part[et * 512 + blockIdx.x] = sm[0];
}

__global__ void scan_single(int* __restrict__ part) {
  int et = blockIdx.x, t = threadIdx.x;
  __shared__ int sm[512];
  int v = (t < NB) ? part[et * 512 + t] : 0;
  sm[t] = v;
  __syncthreads();
  for (int s = 1; s < 512; s <<= 1) {
    int a = (t >= s) ? sm[t - s] : 0;
    __syncthreads();
    sm[t] += a;
    __syncthreads();
  }
  if (t < NB) part[et * 512 + t] = sm[t] - v;  // exclusive
}

__global__ void scan_final(const float* __restrict__ degbase, const int* __restrict__ part,
                           int* __restrict__ offsbase) {
  int et = blockIdx.y, t = threadIdx.x;
  const float* deg = degbase + (size_t)(2 * et + 1) * NNODE;
  int* offs = offsbase + (size_t)et * OSTRIDE;
  __shared__ int sm[256];
  int i = blockIdx.x * 256 + t;
  int v = (i < NNODE) ? (int)deg[i] : 0;
  sm[t] = v;
  __syncthreads();
  for (int s = 1; s < 256; s <<= 1) {
    int a = (t >= s) ? sm[t - s] : 0;
    __syncthreads();
    sm[t] += a;
    __syncthreads();
  }
  int excl = sm[t] - v;
  int base = part[et * 512 + blockIdx.x];
  if (i < NNODE) offs[i] = base + excl;   // segment START; scatter bumps it to END
}

// ---- scatter edges into dst-CSR as interleaved (src, ns[src]) 8B records.
//      offs doubles as the cursor: after this kernel offs[d] == segment end. ----
__global__ void csr_scatter4(
    const int* __restrict__ s0, const int* __restrict__ d0,
    const int* __restrict__ s1, const int* __restrict__ d1,
    const int* __restrict__ s2, const int* __restrict__ d2,
    const int* __restrict__ s3, const int* __restrict__ d3,
    const float* __restrict__ degbase, int* __restrict__ csro,
    int* __restrict__ ewbase, const int* __restrict__ flags) {
  int et = blockIdx.y;
  const int* src = et == 0 ? s0 : et == 1 ? s1 : et == 2 ? s2 : s3;
  const int* dst = et == 0 ? d0 : et == 1 ? d1 : et == 2 ? d2 : d3;
  const float* degs = degbase + (size_t)(2 * et) * NNODE;   // raw src degrees
  int* offs = csro + (size_t)et * OSTRIDE;
  int* ew = ewbase + (size_t)et * 2 * NE;
  int t = blockIdx.x * blockDim.x + threadIdx.x;
  if (t >= NE) return;
  int i64 = flags[1];
  int s = i64 ? src[2 * (size_t)t] : src[t];
  int d = i64 ? dst[2 * (size_t)t] : dst[t];
  int pos = atomicAdd(&offs[d], 1);
  float dg = degs[s];
  union { float f; int i; } u;
  u.f = rsqrtf(dg < 1.0f ? 1.0f : dg);
  int2v v; v[0] = s; v[1] = u.i;
  *(int2v*)(ew + 2 * (size_t)pos) = v;
}

// ---- load EL elements of one x row at flat index base, FMA into acc ----
template <int EL>
__device__ __forceinline__ void accum_row(const void* __restrict__ x, size_t base, float w,
                                          float* acc, int xf) {
  if (xf) {
    const float* xp = (const float*)x + base;
    if constexpr (EL == 8) {
      f32x4 q0 = *(const f32x4*)xp;
      f32x4 q1 = *(const f32x4*)(xp + 4);
#pragma unroll
      for (int i = 0; i < 4; ++i) { acc[i] += w * q0[i]; acc[4 + i] += w * q1[i]; }
    }
  } else {
    const short* xp = (const short*)x + base;
    if constexpr (EL == 8) {
      int4v q = *(const int4v*)xp;
#pragma unroll
      for (int i = 0; i < 4; ++i) {
        unsigned u = (unsigned)q[i];
        union { unsigned u; float f; } lo, hi;
        lo.u = u << 16; hi.u = u & 0xFFFF0000u;
        acc[2 * i] += w * lo.f;
        acc[2 * i + 1] += w * hi.f;
      }
    }
  }
}

// ---- per-destination gather-aggregate, D=512: one wave per dst, 64 lanes x 8 elems.
//      beg = offs[d-1] (post-scatter end of prev), end = offs[d]. ----
__global__ __launch_bounds__(256) void csr_gather_d512(
    const void* __restrict__ x,
    const int* __restrict__ offsA, const int* __restrict__ ewA,
    const float* __restrict__ dgA, short* __restrict__ yA, float* __restrict__ svA,
    const int* __restrict__ offsB, const int* __restrict__ ewB,
    const float* __restrict__ dgB, short* __restrict__ yB, float* __restrict__ svB,
    const int* __restrict__ flags) {
  constexpr int D = 512;
  int which = blockIdx.x & 1;
  int d = (blockIdx.x >> 1) * 4 + (threadIdx.x >> 6);
  int lane = threadIdx.x & 63;
  int xf = flags[0];
  const int* offs = which ? offsB : offsA;
  const int* ew   = which ? ewB : ewA;
  const float* dg = which ? dgB : dgA;
  short* y        = which ? yB : yA;
  float* sv       = which ? svB : svA;

  int beg = d ? offs[d - 1] : 0;
  int end = offs[d];
  float acc[8];
#pragma unroll
  for (int i = 0; i < 8; ++i) acc[i] = 0.f;
  float sw = 0.f;
  int j = beg;
  for (; j + 2 <= end; j += 2) {
    int2v e0 = *(const int2v*)(ew + 2 * (size_t)j);
    int2v e1 = *(const int2v*)(ew + 2 * (size_t)j + 2);
    union { int i; float f; } u0, u1;
    u0.i = e0[1]; u1.i = e1[1];
    sw += u0.f + u1.f;
    accum_row<8>(x, (size_t)e0[0] * D + lane * 8, u0.f, acc, xf);
    accum_row<8>(x, (size_t)e1[0] * D + lane * 8, u1.f, acc, xf);
  }
  if (j < end) {
    int2v e0 = *(const int2v*)(ew + 2 * (size_t)j);
    union { int i; float f; } u0;
    u0.i = e0[1];
    sw += u0.f;
    accum_row<8>(x, (size_t)e0[0] * D + lane * 8, u0.f, acc, xf);
  }
  float dv = dg[d];
  float ndv = rsqrtf(dv < 1.0f ? 1.0f : dv);
  union { short s[8]; int4v v; } o;
#pragma unroll
  for (int i = 0; i < 8; ++i) o.s[i] = f2bf_rne(acc[i] * ndv);
  __builtin_nontemporal_store(o.v, (int4v*)(y + (size_t)d * D + lane * 8));
  if (lane == 0) sv[d] = ndv * sw;
}

// ---- D=256: two dsts per wave (32 lanes x 8 elems each -> 16B bf16 loads) ----
__global__ __launch_bounds__(256) void csr_gather_d256(
    const void* __restrict__ x,
    const int* __restrict__ offsA, const int* __restrict__ ewA,
    const float* __restrict__ dgA, short* __restrict__ yA, float* __restrict__ svA,
    const int* __restrict__ offsB, const int* __restrict__ ewB,
    const float* __restrict__ dgB, short* __restrict__ yB, float* __restrict__ svB,
    const int* __restrict__ flags) {
  constexpr int D = 256;
  int which = blockIdx.x & 1;
  int lane = threadIdx.x & 63;
  int d = (blockIdx.x >> 1) * 8 + (threadIdx.x >> 6) * 2 + (lane >> 5);
  int ln = lane & 31;
  int xf = flags[0];
  const int* offs = which ? offsB : offsA;
  const int* ew   = which ? ewB : ewA;
  const float* dg = which ? dgB : dgA;
  short* y        = which ? yB : yA;
  float* sv       = which ? svB : svA;

  int beg = d ? offs[d - 1] : 0;
  int end = offs[d];
  float acc[8];
#pragma unroll
  for (int i = 0; i < 8; ++i) acc[i] = 0.f;
  float sw = 0.f;
  int j = beg;
  for (; j + 2 <= end; j += 2) {
    int2v e0 = *(const int2v*)(ew + 2 * (size_t)j);
    int2v e1 = *(const int2v*)(ew + 2 * (size_t)j + 2);
    union { int i; float f; } u0, u1;
    u0.i = e0[1]; u1.i = e1[1];
    sw += u0.f + u1.f;
    accum_row<8>(x, (size_t)e0[0] * D + ln * 8, u0.f, acc, xf);
    accum_row<8>(x, (size_t)e1[0] * D + ln * 8, u1.f, acc, xf);
  }
  if (j < end) {
    int2v e0 = *(const int2v*)(ew + 2 * (size_t)j);
    union { int i; float f; } u0;
    u0.i = e0[1];
    sw += u0.f;
    accum_row<8>(x, (size_t)e0[0] * D + ln * 8, u0.f, acc, xf);
  }
  float dv = dg[d];
  float ndv = rsqrtf(dv < 1.0f ? 1.0f : dv);
  union { short s[8]; int4v v; } o;
#pragma unroll
  for (int i = 0; i < 8; ++i) o.s[i] = f2bf_rne(acc[i] * ndv);
  __builtin_nontemporal_store(o.v, (int4v*)(y + (size_t)d * D + ln * 8));
  if (ln == 0) sv[d] = ndv * sw;
}

// ---- VT[n,k] = 0.5 * sum_j Ws[k,j] * We[j,n]   (V = Ws@We, stored transposed, bf16)
__global__ void vt_kernel(const void* __restrict__ Ws, const void* __restrict__ We,
                          short* __restrict__ VT, int Kin, const int* __restrict__ flags) {
  int n = blockIdx.x * 256 + threadIdx.x;   // 0..511
  int k = blockIdx.y;                       // 0..Kin-1
  float acc = 0.f;
  if (flags[0]) {
    const float* wr = (const float*)Ws + (size_t)k * 512;
    const float* we = (const float*)We;
#pragma unroll 8
    for (int j = 0; j < 512; ++j) acc += wr[j] * we[(size_t)j * 512 + n];
  } else {
    const short* wr = (const short*)Ws + (size_t)k * 512;
    const short* we = (const short*)We;
#pragma unroll 8
    for (int j = 0; j < 512; ++j) acc += bf2f(wr[j]) * bf2f(we[(size_t)j * 512 + n]);
  }
  VT[(size_t)n * Kin + k] = f2bf_rne(0.5f * acc);
}

// ---- per-pair column vectors: c{1,2}[n]=0.5*(b_src@W_et)[n], cb[n]=0.5*(b_et1+b_et2)[n]
__global__ void cvec_kernel(const void* __restrict__ b1s, const void* __restrict__ W1,
                            const void* __restrict__ b2s, const void* __restrict__ W2,
                            const void* __restrict__ be1, const void* __restrict__ be2,
                            float* __restrict__ c1, float* __restrict__ c2,
                            float* __restrict__ cb, const int* __restrict__ flags) {
  int n = blockIdx.x * 256 + threadIdx.x;
  float a1 = 0.f, a2 = 0.f, vb1, vb2;
  if (flags[0]) {
    const float* B1 = (const float*)b1s; const float* M1 = (const float*)W1;
    const float* B2 = (const float*)b2s; const float* M2 = (const float*)W2;
    for (int j = 0; j < 512; ++j) {
      a1 += B1[j] * M1[(size_t)j * 512 + n];
      a2 += B2[j] * M2[(size_t)j * 512 + n];
    }
    vb1 = ((const float*)be1)[n]; vb2 = ((const float*)be2)[n];
  } else {
    const short* B1 = (const short*)b1s; const short* M1 = (const short*)W1;
    const short* B2 = (const short*)b2s; const short* M2 = (const short*)W2;
    for (int j = 0; j < 512; ++j) {
      a1 += bf2f(B1[j]) * bf2f(M1[(size_t)j * 512 + n]);
      a2 += bf2f(B2[j]) * bf2f(M2[(size_t)j * 512 + n]);
    }
    vb1 = bf2f(((const short*)be1)[n]); vb2 = bf2f(((const short*)be2)[n]);
  }
  c1[n] = 0.5f * a1;
  c2[n] = 0.5f * a2;
  cb[n] = 0.5f * (vb1 + vb2);
}

// ---- pair GEMM: out[m,n] = [A1|A2]@[B1;B2] (0.5 folded into B)
//                            + s1[m]*c1[n] + s2[m]*c2[n] + cb[n]   (f32 out)
// A1:[M,512] bf16, A2:[M,256] bf16, B1:[512,512] bf16 (B^T rowmajor), B2:[512,256]
__global__ __launch_bounds__(256) void pair_gemm(
    const short* __restrict__ A1, const short* __restrict__ A2,
    const short* __restrict__ B1, const short* __restrict__ B2,
    const float* __restrict__ s1, const float* __restrict__ s2,
    const float* __restrict__ c1, const float* __restrict__ c2,
    const float* __restrict__ cb, float* __restrict__ out, int M) {
  __shared__ __align__(16) short lds_a[128 * 72];   // 64 bf16/row + 16B pad
  __shared__ __align__(16) short lds_b[128 * 72];
  const int tid = threadIdx.x;
  const int bn = blockIdx.x, bm = blockIdx.y;
  const int m0 = bm * 128, n0 = bn * 128;
  const int lane = tid & 63, wave = tid >> 6;
  const int wm = wave & 1, wn = wave >> 1;
  const int lr = lane & 15, lq = lane >> 4;

  f32x4 acc[4][4] = {};

  for (int st = 0; st < 12; ++st) {
    const short* Ap; const short* Bp; int K, k0;
    if (st < 8) { Ap = A1; Bp = B1; K = 512; k0 = st << 6; }
    else        { Ap = A2; Bp = B2; K = 256; k0 = (st - 8) << 6; }

    // stage A: 128 rows x 9 chunks(16B) = 1152 chunks (chunk 8 of each row = pad)
#pragma unroll
    for (int i = 0; i < 5; ++i) {
      int c = tid + i * 256;
      if (c < 1152) {
        int row = c / 9;
        int cc = c - row * 9; if (cc > 7) cc = 7;   // pad chunk: harmless dup load
        int rg = m0 + row; if (rg >= M) rg = M - 1; // clamp tail rows
        const short* gp = Ap + (size_t)rg * K + (size_t)(k0 + (cc << 3));
        __builtin_amdgcn_global_load_lds(
            (const __attribute__((address_space(1))) void*)gp,
            (__attribute__((address_space(3))) void*)(lds_a + ((size_t)c << 3)),
            16, 0, 0);
      }
    }
    // stage B: 128 rows x 9 chunks(16B) = 1152 chunks
#pragma unroll
    for (int i = 0; i < 5; ++i) {
      int c = tid + i * 256;
      if (c < 1152) {
        int row = c / 9;
        int cc = c - row * 9; if (cc > 7) cc = 7;
        const short* gp = Bp + (size_t)(n0 + row) * K + (size_t)(k0 + (cc << 3));
        __builtin_amdgcn_global_load_lds(
            (const __attribute__((address_space(1))) void*)gp,
            (__attribute__((address_space(3))) void*)(lds_b + ((size_t)c << 3)),
            16, 0, 0);
      }
    }
    __syncthreads();

#pragma unroll
    for (int ks = 0; ks < 2; ++ks) {
      short8 bfrag[4];
#pragma unroll
      for (int ni = 0; ni < 4; ++ni) {
        int nl = wn * 64 + ni * 16 + lr;
        bfrag[ni] = *(const short8*)(lds_b + nl * 72 + ks * 32 + lq * 8);
      }
#pragma unroll
      for (int mi = 0; mi < 4; ++mi) {
        int ml = wm * 64 + mi * 16 + lr;
        short8 afrag = *(const short8*)(lds_a + ml * 72 + ks * 32 + lq * 8);
#pragma unroll
        for (int ni = 0; ni < 4; ++ni)
          acc[mi][ni] = __builtin_amdgcn_mfma_f32_16x16x32_bf16(afrag, bfrag[ni], acc[mi][ni], 0, 0, 0);
      }
    }
    __syncthreads();
  }

  // epilogue: C/D layout col=lane&15, row=(lane>>4)*4+reg  [m89-verified]
  float ct1[4], ct2[4], ctb[4]; int gn[4];
#pragma unroll
  for (int ni = 0; ni < 4; ++ni) {
    int n = n0 + wn * 64 + ni * 16 + lr;
    gn[ni] = n; ct1[ni] = c1[n]; ct2[ni] = c2[n]; ctb[ni] = cb[n];
  }
#pragma unroll
  for (int mi = 0; mi < 4; ++mi) {
    int mb = m0 + wm * 64 + mi * 16 + (lq << 2);
#pragma unroll
    for (int r = 0; r < 4; ++r) {
      int m = mb + r;
      if (m < M) {
        float sv1 = s1[m], sv2 = s2[m];
        float* op = out + (size_t)m * 512;
#pragma unroll
        for (int ni = 0; ni < 4; ++ni)
          __builtin_nontemporal_store(
              acc[mi][ni][r] + sv1 * ct1[ni] + sv2 * ct2[ni] + ctb[ni], op + gn[ni]);
      }
    }
  }
}

// ---------------- workspace layout ----------------
static constexpr size_t OFF_Y_DD = 0;                                    // [ND,512] bf16
static constexpr size_t OFF_Y_DG = OFF_Y_DD + (size_t)NNODE * 512 * 2;   // [NG,512] bf16
static constexpr size_t OFF_Y_GD = OFF_Y_DG + (size_t)NNODE * 512 * 2;   // [ND,256] bf16
static constexpr size_t OFF_Y_GG = OFF_Y_GD + (size_t)NNODE * 256 * 2;   // [NG,256] bf16
static constexpr size_t OFF_VT_DD = OFF_Y_GG + (size_t)NNODE * 256 * 2;  // 512x512 bf16
static constexpr size_t OFF_VT_DG = OFF_VT_DD + 512 * 512 * 2;
static constexpr size_t OFF_VT_GD = OFF_VT_DG + 512 * 512 * 2;           // 512x256 bf16
static constexpr size_t OFF_VT_GG = OFF_VT_GD + 512 * 256 * 2;
static constexpr size_t OFF_NRM  = OFF_VT_GG + 512 * 256 * 2;            // 8 x 100000 f32 (raw degs)
static constexpr size_t OFF_SV   = OFF_NRM + 8 * 400000;                 // 4 x 100000 f32
static constexpr size_t OFF_CV   = OFF_SV + 4 * 400000;                  // 6 x 512 f32
static constexpr size_t OFF_FLG  = OFF_CV + 6 * 2048;                    // 2 x int
static constexpr size_t OFF_CSRO = OFF_FLG + 64;                         // 4 x OSTRIDE ints
static constexpr size_t OFF_SRT  = OFF_CSRO + (size_t)4 * OSTRIDE * 4;   // 4 x NE x 8B (src,w)
static constexpr size_t OFF_PART = OFF_SRT + (size_t)4 * 2 * NE * 4;     // 4 x 512 ints
static constexpr size_t WS_NEED  = OFF_PART + 4 * 512 * 4;

extern "C" void kernel_launch(void* const* d_in, const int* in_sizes, int n_in,
                              void* d_out, int out_size, void* d_ws, size_t ws_size,
                              hipStream_t stream) {
  const void* x_d    = d_in[0];
  const void* x_g    = d_in[1];
  const void* W_drug = d_in[2];
  const void* b_drug = d_in[3];
  const void* W_gene = d_in[4];
  const void* b_gene = d_in[5];
  const void* W_dd   = d_in[6];
  const void* b_dd   = d_in[7];
  const void* W_dg   = d_in[8];
  const void* b_dg   = d_in[9];
  const void* W_gd   = d_in[10];
  const void* b_gd   = d_in[11];
  const void* W_gg   = d_in[12];
  const void* b_gg   = d_in[13];
  const int* src_dd = (const int*)d_in[14];
  const int* dst_dd = (const int*)d_in[15];
  const int* src_dg = (const int*)d_in[16];
  const int* dst_dg = (const int*)d_in[17];
  const int* src_gd = (const int*)d_in[18];
  const int* dst_gd = (const int*)d_in[19];
  const int* src_gg = (const int*)d_in[20];
  const int* dst_gg = (const int*)d_in[21];

  if (ws_size < WS_NEED) {
    fprintf(stderr, "kernel_launch: ws too small: have %zu need %zu\n", ws_size, WS_NEED);
    return;
  }

  char* ws = (char*)d_ws;
  short* y_dd = (short*)(ws + OFF_Y_DD);
  short* y_dg = (short*)(ws + OFF_Y_DG);
  short* y_gd = (short*)(ws + OFF_Y_GD);
  short* y_gg = (short*)(ws + OFF_Y_GG);
  short* vt_dd = (short*)(ws + OFF_VT_DD);
  short* vt_dg = (short*)(ws + OFF_VT_DG);
  short* vt_gd = (short*)(ws + OFF_VT_GD);
  short* vt_gg = (short*)(ws + OFF_VT_GG);
  float* degbase = (float*)(ws + OFF_NRM);
  float* dg_dd = degbase + 1 * NNODE;   // raw dst degrees per etype
  float* dg_dg = degbase + 3 * NNODE;
  float* dg_gd = degbase + 5 * NNODE;
  float* dg_gg = degbase + 7 * NNODE;
  float* s_dd = (float*)(ws + OFF_SV + 0 * 400000);
  float* s_gd = (float*)(ws + OFF_SV + 1 * 400000);
  float* s_dg = (float*)(ws + OFF_SV + 2 * 400000);
  float* s_gg = (float*)(ws + OFF_SV + 3 * 400000);
  float* c1_drug = (float*)(ws + OFF_CV + 0 * 2048);
  float* c2_drug = (float*)(ws + OFF_CV + 1 * 2048);
  float* cb_drug = (float*)(ws + OFF_CV + 2 * 2048);
  float* c1_gene = (float*)(ws + OFF_CV + 3 * 2048);
  float* c2_gene = (float*)(ws + OFF_CV + 4 * 2048);
  float* cb_gene = (float*)(ws + OFF_CV + 5 * 2048);
  int* flags = (int*)(ws + OFF_FLG);
  int* csro  = (int*)(ws + OFF_CSRO);    // + et*OSTRIDE
  int* ewbase = (int*)(ws + OFF_SRT);    // + et*2*NE
  int* part  = (int*)(ws + OFF_PART);    // + et*512

  float* out_drug = (float*)d_out;
  float* out_gene = out_drug + (size_t)ND * 512;

  // dtype detection first (independent of memsets)
  detect_kernel<<<1, 256, 0, stream>>>((const unsigned short*)x_d, src_dd, flags);

  // zero degree arrays (y buffers fully written by gathers; offs fully written by scan)
  hipMemsetAsync(ws + OFF_NRM, 0, 8 * 400000, stream);

  // degrees: slots 0..7 = ns_dd,nd_dd,ns_dg,nd_dg,ns_gd,nd_gd,ns_gg,nd_gg (raw counts)
  hist8_kernel<<<dim3(NBE, 8), 256, 0, stream>>>(
      src_dd, dst_dd, src_dg, dst_dg, src_gd, dst_gd, src_gg, dst_gg, degbase, flags);

  // CSR start-offsets from raw dst degrees
  scan_partial<<<dim3(NB, 4), 256, 0, stream>>>(degbase, part);
  scan_single<<<4, 512, 0, stream>>>(part);
  scan_final<<<dim3(NB, 4), 256, 0, stream>>>(degbase, part, csro);

  // combined weights V^T = 0.5*(W_src @ W_et)^T  and bias column vectors
  vt_kernel<<<dim3(2, 512), 256, 0, stream>>>(W_drug, W_dd, vt_dd, 512, flags);
  vt_kernel<<<dim3(2, 512), 256, 0, stream>>>(W_drug, W_dg, vt_dg, 512, flags);
  vt_kernel<<<dim3(2, 256), 256, 0, stream>>>(W_gene, W_gd, vt_gd, 256, flags);
  vt_kernel<<<dim3(2, 256), 256, 0, stream>>>(W_gene, W_gg, vt_gg, 256, flags);
  cvec_kernel<<<2, 256, 0, stream>>>(b_drug, W_dd, b_gene, W_gd, b_dd, b_gd,
                                     c1_drug, c2_drug, cb_drug, flags);
  cvec_kernel<<<2, 256, 0, stream>>>(b_drug, W_dg, b_gene, W_gg, b_dg, b_gg,
                                     c1_gene, c2_gene, cb_gene, flags);

  // build dst-sorted (src, ns[src]) edge records; offs[d] becomes segment END
  csr_scatter4<<<dim3(NBE, 4), 256, 0, stream>>>(
      src_dd, dst_dd, src_dg, dst_dg, src_gd, dst_gd, src_gg, dst_gg,
      degbase, csro, ewbase, flags);

  // gather-aggregate, etype pairs sharing x interleaved for L3 reuse
  csr_gather_d512<<<dim3(2 * (NNODE / 4)), 256, 0, stream>>>(
      x_d, csro + 0 * OSTRIDE, ewbase + 0 * 2 * NE, dg_dd, y_dd, s_dd,
           csro + 1 * OSTRIDE, ewbase + 1 * 2 * NE, dg_dg, y_dg, s_dg, flags);
  csr_gather_d256<<<dim3(2 * (NNODE / 8)), 256, 0, stream>>>(
      x_g, csro + 2 * OSTRIDE, ewbase + 2 * 2 * NE, dg_gd, y_gd, s_gd,
           csro + 3 * OSTRIDE, ewbase + 3 * 2 * NE, dg_gg, y_gg, s_gg, flags);

  // fused pair GEMMs -> f32 outputs
  dim3 gg(4, (ND + 127) / 128);
  pair_gemm<<<gg, 256, 0, stream>>>(y_dd, y_gd, vt_dd, vt_gd, s_dd, s_gd,
                                    c1_drug, c2_drug, cb_drug, out_drug, ND);
  pair_gemm<<<gg, 256, 0, stream>>>(y_dg, y_gg, vt_dg, vt_gg, s_dg, s_gg,
                                    c1_gene, c2_gene, cb_gene, out_gene, NG);
}

// Round 8
// 1309.815 us; speedup vs baseline: 8.8082x; 1.1090x over previous
//
#include <hip/hip_runtime.h>
#include <stdint.h>
#include <stdio.h>

#define ND 100000
#define NG 100000
#define NE 250000
#define NNODE 100000
#define NB 391          // ceil(NNODE/256)
#define NBE 977         // ceil(NE/256)
#define OSTRIDE 100016  // ints per etype in the CSR-offsets region
#define NBLK512 25000   // 2 etypes * NNODE/8 dsts-per-block
#define NBLK256 12500   // 2 etypes * NNODE/16

typedef __attribute__((ext_vector_type(8))) short short8;
typedef __attribute__((ext_vector_type(4))) int   int4v;
typedef __attribute__((ext_vector_type(2))) int   int2v;
typedef __attribute__((ext_vector_type(4))) float f32x4;

__device__ __forceinline__ float bf2f(short s) {
  union { unsigned u; float f; } v;
  v.u = ((unsigned)(unsigned short)s) << 16;
  return v.f;
}
__device__ __forceinline__ short f2bf_rne(float f) {
  union { float f; unsigned u; } v;
  v.f = f;
  unsigned u = v.u + 0x7FFFu + ((v.u >> 16) & 1u);
  return (short)(u >> 16);
}

// ---- dtype detection: flags[0]=features are f32, flags[1]=indices are int64 ----
__global__ void detect_kernel(const unsigned short* __restrict__ xs,
                              const int* __restrict__ idx, int* __restrict__ flags) {
  __shared__ int cnt_huge, cnt_oddnz;
  if (threadIdx.x == 0) { cnt_huge = 0; cnt_oddnz = 0; }
  __syncthreads();
  int t = threadIdx.x;
  int h = 0;
#pragma unroll
  for (int i = 0; i < 8; ++i) {
    unsigned e = ((unsigned)xs[t * 8 + i] >> 7) & 0xFFu;
    if (e >= 0xC0u) ++h;  // |v| >= 2^65 or Inf/NaN: impossible for N(0,1) bf16 data
  }
  if (h) atomicAdd(&cnt_huge, h);
  if (t < 128 && idx[2 * t + 1] != 0) atomicAdd(&cnt_oddnz, 1);
  __syncthreads();
  if (t == 0) {
    flags[0] = (cnt_huge > 8) ? 1 : 0;
    flags[1] = (cnt_oddnz == 0) ? 1 : 0;  // int64: odd words all zero (values < 2^31)
  }
}

// ---- merged degree histograms: slot y in [0,8), deg[slot][idx[e]] += 1 ----
__global__ void hist8_kernel(const int* __restrict__ i0, const int* __restrict__ i1,
                             const int* __restrict__ i2, const int* __restrict__ i3,
                             const int* __restrict__ i4, const int* __restrict__ i5,
                             const int* __restrict__ i6, const int* __restrict__ i7,
                             float* __restrict__ degbase, const int* __restrict__ flags) {
  int slot = blockIdx.y;
  const int* idx = slot == 0 ? i0 : slot == 1 ? i1 : slot == 2 ? i2 : slot == 3 ? i3
                 : slot == 4 ? i4 : slot == 5 ? i5 : slot == 6 ? i6 : i7;
  int t = blockIdx.x * blockDim.x + threadIdx.x;
  if (t < NE) {
    int v = flags[1] ? idx[2 * (size_t)t] : idx[t];
    atomicAdd(degbase + (size_t)slot * NNODE + v, 1.0f);
  }
}

// ============ CSR build: 3-kernel exclusive scan over dst degrees + scatter ============
// dst-degree array for etype et lives at degbase + (2*et+1)*NNODE (RAW counts).

__global__ void scan_partial(const float* __restrict__ degbase, int* __restrict__ part) {
  int et = blockIdx.y, t = threadIdx.x;
  const float* deg = degbase + (size_t)(2 * et + 1) * NNODE;
  __shared__ int sm[256];
  int i = blockIdx.x * 256 + t;
  int v = (i < NNODE) ? (int)deg[i] : 0;
  sm[t] = v;
  __syncthreads();
  for (int s = 128; s > 0; s >>= 1) {
    if (t < s) sm[t] += sm[t + s];
    __syncthreads();
  }
  if (t == 0) part[et * 512 + blockIdx.x] = sm[0];
}

__global__ void scan_single(int* __restrict__ part) {
  int et = blockIdx.x, t = threadIdx.x;
  __shared__ int sm[512];
  int v = (t < NB) ? part[et * 512 + t] : 0;
  sm[t] = v;
  __syncthreads();
  for (int s = 1; s < 512; s <<= 1) {
    int a = (t >= s) ? sm[t - s] : 0;
    __syncthreads();
    sm[t] += a;
    __syncthreads();
  }
  if (t < NB) part[et * 512 + t] = sm[t] - v;  // exclusive
}

__global__ void scan_final(const float* __restrict__ degbase, const int* __restrict__ part,
                           int* __restrict__ offsbase) {
  int et = blockIdx.y, t = threadIdx.x;
  const float* deg = degbase + (size_t)(2 * et + 1) * NNODE;
  int* offs = offsbase + (size_t)et * OSTRIDE;
  __shared__ int sm[256];
  int i = blockIdx.x * 256 + t;
  int v = (i < NNODE) ? (int)deg[i] : 0;
  sm[t] = v;
  __syncthreads();
  for (int s = 1; s < 256; s <<= 1) {
    int a = (t >= s) ? sm[t - s] : 0;
    __syncthreads();
    sm[t] += a;
    __syncthreads();
  }
  int excl = sm[t] - v;
  int base = part[et * 512 + blockIdx.x];
  if (i < NNODE) offs[i] = base + excl;   // segment START; scatter bumps it to END
}

// ---- scatter edges into dst-CSR as interleaved (src, ns[src]) 8B records.
//      offs doubles as the cursor: after this kernel offs[d] == segment end. ----
__global__ void csr_scatter4(
    const int* __restrict__ s0, const int* __restrict__ d0,
    const int* __restrict__ s1, const int* __restrict__ d1,
    const int* __restrict__ s2, const int* __restrict__ d2,
    const int* __restrict__ s3, const int* __restrict__ d3,
    const float* __restrict__ degbase, int* __restrict__ csro,
    int* __restrict__ ewbase, const int* __restrict__ flags) {
  int et = blockIdx.y;
  const int* src = et == 0 ? s0 : et == 1 ? s1 : et == 2 ? s2 : s3;
  const int* dst = et == 0 ? d0 : et == 1 ? d1 : et == 2 ? d2 : d3;
  const float* degs = degbase + (size_t)(2 * et) * NNODE;   // raw src degrees
  int* offs = csro + (size_t)et * OSTRIDE;
  int* ew = ewbase + (size_t)et * 2 * NE;
  int t = blockIdx.x * blockDim.x + threadIdx.x;
  if (t >= NE) return;
  int i64 = flags[1];
  int s = i64 ? src[2 * (size_t)t] : src[t];
  int d = i64 ? dst[2 * (size_t)t] : dst[t];
  int pos = atomicAdd(&offs[d], 1);
  float dg = degs[s];
  union { float f; int i; } u;
  u.f = rsqrtf(dg < 1.0f ? 1.0f : dg);
  int2v v; v[0] = s; v[1] = u.i;
  *(int2v*)(ew + 2 * (size_t)pos) = v;
}

// ---- load 8 elements of one x row at flat element index base, FMA into acc ----
__device__ __forceinline__ void accum_row8(const void* __restrict__ x, size_t base, float w,
                                           float* acc, int xf) {
  if (xf) {
    const float* xp = (const float*)x + base;
    f32x4 q0 = *(const f32x4*)xp;
    f32x4 q1 = *(const f32x4*)(xp + 4);
#pragma unroll
    for (int i = 0; i < 4; ++i) { acc[i] += w * q0[i]; acc[4 + i] += w * q1[i]; }
  } else {
    const short* xp = (const short*)x + base;
    int4v q = *(const int4v*)xp;
#pragma unroll
    for (int i = 0; i < 4; ++i) {
      unsigned u = (unsigned)q[i];
      union { unsigned u; float f; } lo, hi;
      lo.u = u << 16; hi.u = u & 0xFFFF0000u;
      acc[2 * i] += w * lo.f;
      acc[2 * i + 1] += w * hi.f;
    }
  }
}

// ---- one destination's aggregate: edge loop + bf16 row store + sv ----
template <int D>
__device__ __forceinline__ void gather_one(
    const void* __restrict__ x, const int* __restrict__ offs, const int* __restrict__ ew,
    const float* __restrict__ dg, short* __restrict__ y, float* __restrict__ sv,
    int d, int ln, int xf) {
  int beg = d ? offs[d - 1] : 0;
  int end = offs[d];
  float acc[8];
#pragma unroll
  for (int i = 0; i < 8; ++i) acc[i] = 0.f;
  float sw = 0.f;
  int j = beg;
  for (; j + 2 <= end; j += 2) {
    int2v e0 = *(const int2v*)(ew + 2 * (size_t)j);
    int2v e1 = *(const int2v*)(ew + 2 * (size_t)j + 2);
    union { int i; float f; } u0, u1;
    u0.i = e0[1]; u1.i = e1[1];
    sw += u0.f + u1.f;
    accum_row8(x, (size_t)e0[0] * D + ln * 8, u0.f, acc, xf);
    accum_row8(x, (size_t)e1[0] * D + ln * 8, u1.f, acc, xf);
  }
  if (j < end) {
    int2v e0 = *(const int2v*)(ew + 2 * (size_t)j);
    union { int i; float f; } u0;
    u0.i = e0[1];
    sw += u0.f;
    accum_row8(x, (size_t)e0[0] * D + ln * 8, u0.f, acc, xf);
  }
  float dv = dg[d];
  float ndv = rsqrtf(dv < 1.0f ? 1.0f : dv);
  union { short s[8]; int4v v; } o;
#pragma unroll
  for (int i = 0; i < 8; ++i) o.s[i] = f2bf_rne(acc[i] * ndv);
  __builtin_nontemporal_store(o.v, (int4v*)(y + (size_t)d * D + ln * 8));
  if (ln == 0) sv[d] = ndv * sw;
}

// ---- fused gather: blocks [0,NBLK512) = dd/dg over x_d (D=512, 1 dst/wave/iter);
//      blocks [NBLK512, NBLK512+NBLK256) = gd/gg over x_g (D=256, 2 dsts/wave/iter).
//      Parity interleaves the two etypes sharing one x for L3 temporal reuse. ----
__global__ __launch_bounds__(256) void gather_all(
    const void* __restrict__ xd, const void* __restrict__ xg,
    const int* __restrict__ o0, const int* __restrict__ e0,
    const float* __restrict__ g0, short* __restrict__ y0, float* __restrict__ v0,
    const int* __restrict__ o1, const int* __restrict__ e1,
    const float* __restrict__ g1, short* __restrict__ y1, float* __restrict__ v1,
    const int* __restrict__ o2, const int* __restrict__ e2,
    const float* __restrict__ g2, short* __restrict__ y2, float* __restrict__ v2,
    const int* __restrict__ o3, const int* __restrict__ e3,
    const float* __restrict__ g3, short* __restrict__ y3, float* __restrict__ v3,
    const int* __restrict__ flags) {
  int b = blockIdx.x;
  int tid = threadIdx.x;
  int wave = tid >> 6, lane = tid & 63;
  int xf = flags[0];
  if (b < NBLK512) {
    int which = b & 1, g = b >> 1;
    const int* offs = which ? o1 : o0;
    const int* ew   = which ? e1 : e0;
    const float* dg = which ? g1 : g0;
    short* y        = which ? y1 : y0;
    float* sv       = which ? v1 : v0;
#pragma unroll
    for (int ii = 0; ii < 2; ++ii) {
      int d = g * 8 + wave * 2 + ii;
      gather_one<512>(xd, offs, ew, dg, y, sv, d, lane, xf);
    }
  } else {
    int b2 = b - NBLK512;
    int which = b2 & 1, g = b2 >> 1;
    const int* offs = which ? o3 : o2;
    const int* ew   = which ? e3 : e2;
    const float* dg = which ? g3 : g2;
    short* y        = which ? y3 : y2;
    float* sv       = which ? v3 : v2;
    int ln = lane & 31, hb = lane >> 5;
#pragma unroll
    for (int ii = 0; ii < 2; ++ii) {
      int d = g * 16 + wave * 4 + ii * 2 + hb;
      gather_one<256>(xg, offs, ew, dg, y, sv, d, ln, xf);
    }
  }
}

// ---- fused weight prep: blocks 0..3071 = vt jobs, 3072..3075 = cvec jobs ----
// vt: VT[n,k] = 0.5 * sum_j Ws[k,j] * We[j,n]  (bf16 out, B^T rowmajor [512][Kin])
// cvec: c{1,2}[n] = 0.5*(b_src@W_et)[n], cb[n] = 0.5*(b_et1+b_et2)[n]
__global__ void prep_weights(
    const void* __restrict__ W_drug, const void* __restrict__ W_gene,
    const void* __restrict__ W_dd, const void* __restrict__ W_dg,
    const void* __restrict__ W_gd, const void* __restrict__ W_gg,
    const void* __restrict__ b_drug, const void* __restrict__ b_gene,
    const void* __restrict__ b_dd, const void* __restrict__ b_dg,
    const void* __restrict__ b_gd, const void* __restrict__ b_gg,
    short* __restrict__ vt_dd, short* __restrict__ vt_dg,
    short* __restrict__ vt_gd, short* __restrict__ vt_gg,
    float* __restrict__ c1_drug, float* __restrict__ c2_drug, float* __restrict__ cb_drug,
    float* __restrict__ c1_gene, float* __restrict__ c2_gene, float* __restrict__ cb_gene,
    const int* __restrict__ flags) {
  int b = blockIdx.x, tid = threadIdx.x;
  int xf = flags[0];
  if (b < 3072) {
    const void* Ws; const void* We; short* VT; int Kin, local;
    if (b < 1024)      { Ws = W_drug; We = W_dd; VT = vt_dd; Kin = 512; local = b; }
    else if (b < 2048) { Ws = W_drug; We = W_dg; VT = vt_dg; Kin = 512; local = b - 1024; }
    else if (b < 2560) { Ws = W_gene; We = W_gd; VT = vt_gd; Kin = 256; local = b - 2048; }
    else               { Ws = W_gene; We = W_gg; VT = vt_gg; Kin = 256; local = b - 2560; }
    int k = local >> 1;
    int n = (local & 1) * 256 + tid;
    float acc = 0.f;
    if (xf) {
      const float* wr = (const float*)Ws + (size_t)k * 512;
      const float* we = (const float*)We;
#pragma unroll 8
      for (int j = 0; j < 512; ++j) acc += wr[j] * we[(size_t)j * 512 + n];
    } else {
      const short* wr = (const short*)Ws + (size_t)k * 512;
      const short* we = (const short*)We;
#pragma unroll 8
      for (int j = 0; j < 512; ++j) acc += bf2f(wr[j]) * bf2f(we[(size_t)j * 512 + n]);
    }
    VT[(size_t)n * Kin + k] = f2bf_rne(0.5f * acc);
  } else {
    int local = b - 3072;
    int job = local >> 1;               // 0 = drug pair, 1 = gene pair
    int n = (local & 1) * 256 + tid;
    const void* b1s = b_drug;
    const void* W1 = job ? W_dg : W_dd;
    const void* b2s = b_gene;
    const void* W2 = job ? W_gg : W_gd;
    const void* be1 = job ? b_dg : b_dd;
    const void* be2 = job ? b_gg : b_gd;
    float* c1 = job ? c1_gene : c1_drug;
    float* c2 = job ? c2_gene : c2_drug;
    float* cb = job ? cb_gene : cb_drug;
    float a1 = 0.f, a2 = 0.f, vb1, vb2;
    if (xf) {
      const float* B1 = (const float*)b1s; const float* M1 = (const float*)W1;
      const float* B2 = (const float*)b2s; const float* M2 = (const float*)W2;
      for (int j = 0; j < 512; ++j) {
        a1 += B1[j] * M1[(size_t)j * 512 + n];
        a2 += B2[j] * M2[(size_t)j * 512 + n];
      }
      vb1 = ((const float*)be1)[n]; vb2 = ((const float*)be2)[n];
    } else {
      const short* B1 = (const short*)b1s; const short* M1 = (const short*)W1;
      const short* B2 = (const short*)b2s; const short* M2 = (const short*)W2;
      for (int j = 0; j < 512; ++j) {
        a1 += bf2f(B1[j]) * bf2f(M1[(size_t)j * 512 + n]);
        a2 += bf2f(B2[j]) * bf2f(M2[(size_t)j * 512 + n]);
      }
      vb1 = bf2f(((const short*)be1)[n]); vb2 = bf2f(((const short*)be2)[n]);
    }
    c1[n] = 0.5f * a1;
    c2[n] = 0.5f * a2;
    cb[n] = 0.5f * (vb1 + vb2);
  }
}

// ---- fused pair GEMM (both output ntypes in one launch, blockIdx.z selects):
// out[m,n] = [A1|A2]@[B1;B2] (0.5 folded into B) + s1[m]*c1[n] + s2[m]*c2[n] + cb[n]
// A1:[M,512] bf16, A2:[M,256] bf16, B1:[512,512] bf16 (B^T rowmajor), B2:[512,256]
__global__ __launch_bounds__(256) void pair_gemm2(
    const short* __restrict__ A1a, const short* __restrict__ A2a,
    const short* __restrict__ B1a, const short* __restrict__ B2a,
    const float* __restrict__ s1a, const float* __restrict__ s2a,
    const float* __restrict__ c1a, const float* __restrict__ c2a,
    const float* __restrict__ cba, float* __restrict__ outa,
    const short* __restrict__ A1b, const short* __restrict__ A2b,
    const short* __restrict__ B1b, const short* __restrict__ B2b,
    const float* __restrict__ s1b, const float* __restrict__ s2b,
    const float* __restrict__ c1b, const float* __restrict__ c2b,
    const float* __restrict__ cbb, float* __restrict__ outb, int M) {
  __shared__ __align__(16) short lds_a[128 * 72];   // 64 bf16/row + 16B pad
  __shared__ __align__(16) short lds_b[128 * 72];
  const int z = blockIdx.z;
  const short* A1 = z ? A1b : A1a;
  const short* A2 = z ? A2b : A2a;
  const short* B1 = z ? B1b : B1a;
  const short* B2 = z ? B2b : B2a;
  const float* s1 = z ? s1b : s1a;
  const float* s2 = z ? s2b : s2a;
  const float* c1 = z ? c1b : c1a;
  const float* c2 = z ? c2b : c2a;
  const float* cb = z ? cbb : cba;
  float* out      = z ? outb : outa;

  const int tid = threadIdx.x;
  const int bn = blockIdx.x, bm = blockIdx.y;
  const int m0 = bm * 128, n0 = bn * 128;
  const int lane = tid & 63, wave = tid >> 6;
  const int wm = wave & 1, wn = wave >> 1;
  const int lr = lane & 15, lq = lane >> 4;

  f32x4 acc[4][4] = {};

  for (int st = 0; st < 12; ++st) {
    const short* Ap; const short* Bp; int K, k0;
    if (st < 8) { Ap = A1; Bp = B1; K = 512; k0 = st << 6; }
    else        { Ap = A2; Bp = B2; K = 256; k0 = (st - 8) << 6; }

    // stage A: 128 rows x 9 chunks(16B) = 1152 chunks (chunk 8 of each row = pad)
#pragma unroll
    for (int i = 0; i < 5; ++i) {
      int c = tid + i * 256;
      if (c < 1152) {
        int row = c / 9;
        int cc = c - row * 9; if (cc > 7) cc = 7;   // pad chunk: harmless dup load
        int rg = m0 + row; if (rg >= M) rg = M - 1; // clamp tail rows
        const short* gp = Ap + (size_t)rg * K + (size_t)(k0 + (cc << 3));
        __builtin_amdgcn_global_load_lds(
            (const __attribute__((address_space(1))) void*)gp,
            (__attribute__((address_space(3))) void*)(lds_a + ((size_t)c << 3)),
            16, 0, 0);
      }
    }
    // stage B: 128 rows x 9 chunks(16B) = 1152 chunks
#pragma unroll
    for (int i = 0; i < 5; ++i) {
      int c = tid + i * 256;
      if (c < 1152) {
        int row = c / 9;
        int cc = c - row * 9; if (cc > 7) cc = 7;
        const short* gp = Bp + (size_t)(n0 + row) * K + (size_t)(k0 + (cc << 3));
        __builtin_amdgcn_global_load_lds(
            (const __attribute__((address_space(1))) void*)gp,
            (__attribute__((address_space(3))) void*)(lds_b + ((size_t)c << 3)),
            16, 0, 0);
      }
    }
    __syncthreads();

#pragma unroll
    for (int ks = 0; ks < 2; ++ks) {
      short8 bfrag[4];
#pragma unroll
      for (int ni = 0; ni < 4; ++ni) {
        int nl = wn * 64 + ni * 16 + lr;
        bfrag[ni] = *(const short8*)(lds_b + nl * 72 + ks * 32 + lq * 8);
      }
#pragma unroll
      for (int mi = 0; mi < 4; ++mi) {
        int ml = wm * 64 + mi * 16 + lr;
        short8 afrag = *(const short8*)(lds_a + ml * 72 + ks * 32 + lq * 8);
#pragma unroll
        for (int ni = 0; ni < 4; ++ni)
          acc[mi][ni] = __builtin_amdgcn_mfma_f32_16x16x32_bf16(afrag, bfrag[ni], acc[mi][ni], 0, 0, 0);
      }
    }
    __syncthreads();
  }

  // epilogue: C/D layout col=lane&15, row=(lane>>4)*4+reg  [m89-verified]
  float ct1[4], ct2[4], ctb[4]; int gn[4];
#pragma unroll
  for (int ni = 0; ni < 4; ++ni) {
    int n = n0 + wn * 64 + ni * 16 + lr;
    gn[ni] = n; ct1[ni] = c1[n]; ct2[ni] = c2[n]; ctb[ni] = cb[n];
  }
#pragma unroll
  for (int mi = 0; mi < 4; ++mi) {
    int mb = m0 + wm * 64 + mi * 16 + (lq << 2);
#pragma unroll
    for (int r = 0; r < 4; ++r) {
      int m = mb + r;
      if (m < M) {
        float sv1 = s1[m], sv2 = s2[m];
        float* op = out + (size_t)m * 512;
#pragma unroll
        for (int ni = 0; ni < 4; ++ni)
          __builtin_nontemporal_store(
              acc[mi][ni][r] + sv1 * ct1[ni] + sv2 * ct2[ni] + ctb[ni], op + gn[ni]);
      }
    }
  }
}

// ---------------- workspace layout ----------------
static constexpr size_t OFF_Y_DD = 0;                                    // [ND,512] bf16
static constexpr size_t OFF_Y_DG = OFF_Y_DD + (size_t)NNODE * 512 * 2;   // [NG,512] bf16
static constexpr size_t OFF_Y_GD = OFF_Y_DG + (size_t)NNODE * 512 * 2;   // [ND,256] bf16
static constexpr size_t OFF_Y_GG = OFF_Y_GD + (size_t)NNODE * 256 * 2;   // [NG,256] bf16
static constexpr size_t OFF_VT_DD = OFF_Y_GG + (size_t)NNODE * 256 * 2;  // 512x512 bf16
static constexpr size_t OFF_VT_DG = OFF_VT_DD + 512 * 512 * 2;
static constexpr size_t OFF_VT_GD = OFF_VT_DG + 512 * 512 * 2;           // 512x256 bf16
static constexpr size_t OFF_VT_GG = OFF_VT_GD + 512 * 256 * 2;
static constexpr size_t OFF_NRM  = OFF_VT_GG + 512 * 256 * 2;            // 8 x 100000 f32 (raw degs)
static constexpr size_t OFF_SV   = OFF_NRM + 8 * 400000;                 // 4 x 100000 f32
static constexpr size_t OFF_CV   = OFF_SV + 4 * 400000;                  // 6 x 512 f32
static constexpr size_t OFF_FLG  = OFF_CV + 6 * 2048;                    // 2 x int
static constexpr size_t OFF_CSRO = OFF_FLG + 64;                         // 4 x OSTRIDE ints
static constexpr size_t OFF_SRT  = OFF_CSRO + (size_t)4 * OSTRIDE * 4;   // 4 x NE x 8B (src,w)
static constexpr size_t OFF_PART = OFF_SRT + (size_t)4 * 2 * NE * 4;     // 4 x 512 ints
static constexpr size_t WS_NEED  = OFF_PART + 4 * 512 * 4;

extern "C" void kernel_launch(void* const* d_in, const int* in_sizes, int n_in,
                              void* d_out, int out_size, void* d_ws, size_t ws_size,
                              hipStream_t stream) {
  const void* x_d    = d_in[0];
  const void* x_g    = d_in[1];
  const void* W_drug = d_in[2];
  const void* b_drug = d_in[3];
  const void* W_gene = d_in[4];
  const void* b_gene = d_in[5];
  const void* W_dd   = d_in[6];
  const void* b_dd   = d_in[7];
  const void* W_dg   = d_in[8];
  const void* b_dg   = d_in[9];
  const void* W_gd   = d_in[10];
  const void* b_gd   = d_in[11];
  const void* W_gg   = d_in[12];
  const void* b_gg   = d_in[13];
  const int* src_dd = (const int*)d_in[14];
  const int* dst_dd = (const int*)d_in[15];
  const int* src_dg = (const int*)d_in[16];
  const int* dst_dg = (const int*)d_in[17];
  const int* src_gd = (const int*)d_in[18];
  const int* dst_gd = (const int*)d_in[19];
  const int* src_gg = (const int*)d_in[20];
  const int* dst_gg = (const int*)d_in[21];

  if (ws_size < WS_NEED) {
    fprintf(stderr, "kernel_launch: ws too small: have %zu need %zu\n", ws_size, WS_NEED);
    return;
  }

  char* ws = (char*)d_ws;
  short* y_dd = (short*)(ws + OFF_Y_DD);
  short* y_dg = (short*)(ws + OFF_Y_DG);
  short* y_gd = (short*)(ws + OFF_Y_GD);
  short* y_gg = (short*)(ws + OFF_Y_GG);
  short* vt_dd = (short*)(ws + OFF_VT_DD);
  short* vt_dg = (short*)(ws + OFF_VT_DG);
  short* vt_gd = (short*)(ws + OFF_VT_GD);
  short* vt_gg = (short*)(ws + OFF_VT_GG);
  float* degbase = (float*)(ws + OFF_NRM);
  float* dg_dd = degbase + 1 * NNODE;   // raw dst degrees per etype
  float* dg_dg = degbase + 3 * NNODE;
  float* dg_gd = degbase + 5 * NNODE;
  float* dg_gg = degbase + 7 * NNODE;
  float* s_dd = (float*)(ws + OFF_SV + 0 * 400000);
  float* s_gd = (float*)(ws + OFF_SV + 1 * 400000);
  float* s_dg = (float*)(ws + OFF_SV + 2 * 400000);
  float* s_gg = (float*)(ws + OFF_SV + 3 * 400000);
  float* c1_drug = (float*)(ws + OFF_CV + 0 * 2048);
  float* c2_drug = (float*)(ws + OFF_CV + 1 * 2048);
  float* cb_drug = (float*)(ws + OFF_CV + 2 * 2048);
  float* c1_gene = (float*)(ws + OFF_CV + 3 * 2048);
  float* c2_gene = (float*)(ws + OFF_CV + 4 * 2048);
  float* cb_gene = (float*)(ws + OFF_CV + 5 * 2048);
  int* flags = (int*)(ws + OFF_FLG);
  int* csro  = (int*)(ws + OFF_CSRO);    // + et*OSTRIDE
  int* ewbase = (int*)(ws + OFF_SRT);    // + et*2*NE
  int* part  = (int*)(ws + OFF_PART);    // + et*512

  float* out_drug = (float*)d_out;
  float* out_gene = out_drug + (size_t)ND * 512;

  // dtype detection first (independent of memsets)
  detect_kernel<<<1, 256, 0, stream>>>((const unsigned short*)x_d, src_dd, flags);

  // zero degree arrays (y buffers fully written by gathers; offs fully written by scan)
  hipMemsetAsync(ws + OFF_NRM, 0, 8 * 400000, stream);

  // degrees: slots 0..7 = ns_dd,nd_dd,ns_dg,nd_dg,ns_gd,nd_gd,ns_gg,nd_gg (raw counts)
  hist8_kernel<<<dim3(NBE, 8), 256, 0, stream>>>(
      src_dd, dst_dd, src_dg, dst_dg, src_gd, dst_gd, src_gg, dst_gg, degbase, flags);

  // CSR start-offsets from raw dst degrees
  scan_partial<<<dim3(NB, 4), 256, 0, stream>>>(degbase, part);
  scan_single<<<4, 512, 0, stream>>>(part);
  scan_final<<<dim3(NB, 4), 256, 0, stream>>>(degbase, part, csro);

  // fused combined-weight + bias-vector prep (was 4 vt + 2 cvec launches)
  prep_weights<<<3076, 256, 0, stream>>>(
      W_drug, W_gene, W_dd, W_dg, W_gd, W_gg,
      b_drug, b_gene, b_dd, b_dg, b_gd, b_gg,
      vt_dd, vt_dg, vt_gd, vt_gg,
      c1_drug, c2_drug, cb_drug, c1_gene, c2_gene, cb_gene, flags);

  // build dst-sorted (src, ns[src]) edge records; offs[d] becomes segment END
  csr_scatter4<<<dim3(NBE, 4), 256, 0, stream>>>(
      src_dd, dst_dd, src_dg, dst_dg, src_gd, dst_gd, src_gg, dst_gg,
      degbase, csro, ewbase, flags);

  // fused gather-aggregate (all 4 etypes, one launch)
  gather_all<<<NBLK512 + NBLK256, 256, 0, stream>>>(
      x_d, x_g,
      csro + 0 * OSTRIDE, ewbase + 0 * 2 * NE, dg_dd, y_dd, s_dd,
      csro + 1 * OSTRIDE, ewbase + 1 * 2 * NE, dg_dg, y_dg, s_dg,
      csro + 2 * OSTRIDE, ewbase + 2 * 2 * NE, dg_gd, y_gd, s_gd,
      csro + 3 * OSTRIDE, ewbase + 3 * 2 * NE, dg_gg, y_gg, s_gg, flags);

  // fused pair GEMMs -> f32 outputs (z=0: drug, z=1: gene)
  dim3 gg(4, (ND + 127) / 128, 2);
  pair_gemm2<<<gg, 256, 0, stream>>>(
      y_dd, y_gd, vt_dd, vt_gd, s_dd, s_gd, c1_drug, c2_drug, cb_drug, out_drug,
      y_dg, y_gg, vt_dg, vt_gg, s_dg, s_gg, c1_gene, c2_gene, cb_gene, out_gene, ND);
}